// Round 2
// baseline (12003.430 us; speedup 1.0000x reference)
//
#include <hip/hip_runtime.h>
#include <hip/hip_bf16.h>
#include <hip/hip_cooperative_groups.h>
#include <math.h>

namespace cg = cooperative_groups;

#define BB 64
#define NPIX 196
#define ENCD 2048
#define DECD 512
#define VOCAB_N 10000
#define MAXLEN 52
#define TT 51
#define NOUT 12608   // cols: [0,10048) W_fc(10000+48 pad) | [10048,12096) W_fbeta | [12096,12608) W_dec_att

// Output layout (floats): preds | captions | declens | alphas
#define PRED_SZ   (BB * TT * VOCAB_N)
#define CAPS_SZ   (BB * MAXLEN)
#define LENS_SZ   (BB)
#define ALPHAS_OFF (PRED_SZ + CAPS_SZ + LENS_SZ)

typedef __attribute__((ext_vector_type(8))) short short8;
typedef __attribute__((ext_vector_type(4))) float f32x4;

__device__ __forceinline__ float fsigm(float x) {
    return 1.0f / (1.0f + __expf(-x));
}
__device__ __forceinline__ float ftanh(float x) {
    x = fminf(fmaxf(x, -15.0f), 15.0f);
    float e = __expf(2.0f * x);
    return (e - 1.0f) / (e + 1.0f);
}
__device__ __forceinline__ float bf2f(unsigned short u) {
    union { unsigned int i; float f; } v;
    v.i = ((unsigned int)u) << 16;
    return v.f;
}
__device__ __forceinline__ unsigned short f2bf(float f) {
    union { float f; unsigned int i; } v;
    v.f = f;
    unsigned int r = v.i + 0x7FFFu + ((v.i >> 16) & 1u);
    return (unsigned short)(r >> 16);
}

// ---------------------------------------------------------------------------
// Mega-kernel arg block
// ---------------------------------------------------------------------------
struct DecP {
    const unsigned short* attenc16;
    const unsigned short* enc16;
    unsigned short* xcat;      // [BB][3072]: emb | gate*awe | h
    float* gadec;              // [BB][2560]: gate(2048) | adec(512)
    float* gparts;             // [8][BB][2048]
    float* c;                  // [BB][512]
    const float* Wf;           // W_full_att (512)
    const float* bfull;        // b_full_att (1)
    const float* emb;          // [VOCAB][512]
    const int* caps;
    const int* lens;
    const unsigned short* WpL; // gates weights, K=3072, Npad=2048 (96 kb)
    const unsigned short* WpO; // fc|fbeta|dec_att, K=512, Npad=NOUT (16 kb)
    const float* bcat2;        // [NOUT]
    const float* bsum;         // [2048]
    float* out;
};

// ---------------------------------------------------------------------------
// Phase A: attention + awe + xcat build.  blocks 0..63 (b = blockIdx.x), 256 thr
// ---------------------------------------------------------------------------
__device__ __forceinline__ void attawe_phase(const DecP& P, int t)
{
    __shared__ float av[512];
    __shared__ float wv[512];
    __shared__ float es[NPIX];
    __shared__ float alpha_s[NPIX];
    __shared__ float r4[4];
    __shared__ float smax, ssum;

    const int b = blockIdx.x;
    const int tid = threadIdx.x;
    const int lane = tid & 63, wid = tid >> 6;

    for (int j = tid; j < 512; j += 256) {
        av[j] = P.gadec[(size_t)b * 2560 + 2048 + j];
        wv[j] = P.Wf[j];
    }
    __syncthreads();

    float mya[8], myw[8];
#pragma unroll
    for (int i = 0; i < 8; ++i) {
        mya[i] = av[lane * 8 + i];
        myw[i] = wv[lane * 8 + i];
    }

    float bf0 = P.bfull[0];
    for (int p = wid; p < NPIX; p += 4) {
        const unsigned short* ae = P.attenc16 + ((size_t)(b * NPIX + p)) * 512 + lane * 8;
        short8 e8 = *(const short8*)ae;
        float s = 0.f;
#pragma unroll
        for (int i = 0; i < 8; ++i)
            s += ftanh(bf2f((unsigned short)e8[i]) + mya[i]) * myw[i];
        for (int off = 32; off; off >>= 1) s += __shfl_down(s, off);
        if (lane == 0) es[p] = s + bf0;
    }
    __syncthreads();

    float v = (tid < NPIX) ? es[tid] : -1e30f;
    float m = v;
    for (int off = 32; off; off >>= 1) m = fmaxf(m, __shfl_down(m, off));
    if (lane == 0) r4[wid] = m;
    __syncthreads();
    if (tid == 0) smax = fmaxf(fmaxf(r4[0], r4[1]), fmaxf(r4[2], r4[3]));
    __syncthreads();

    float ev = (tid < NPIX) ? __expf(v - smax) : 0.0f;
    float s = ev;
    for (int off = 32; off; off >>= 1) s += __shfl_down(s, off);
    if (lane == 0) r4[wid] = s;
    __syncthreads();
    if (tid == 0) ssum = r4[0] + r4[1] + r4[2] + r4[3];
    __syncthreads();

    float mk = (t < P.lens[b] - 1) ? 1.0f : 0.0f;
    if (tid < NPIX) {
        float a = ev / ssum;
        alpha_s[tid] = a;
        P.out[ALPHAS_OFF + ((size_t)b * TT + t) * NPIX + tid] = a * mk;
    }
    __syncthreads();

    // awe: 8 d's per thread (256*8 = 2048)
    int d0 = tid * 8;
    const unsigned short* e = P.enc16 + (size_t)b * NPIX * ENCD + d0;
    float sa[8];
#pragma unroll
    for (int j = 0; j < 8; ++j) sa[j] = 0.f;
#pragma unroll 4
    for (int p = 0; p < NPIX; ++p) {
        short8 v8 = *(const short8*)(e + (size_t)p * ENCD);
        float a = alpha_s[p];
#pragma unroll
        for (int j = 0; j < 8; ++j) sa[j] += a * bf2f((unsigned short)v8[j]);
    }
    unsigned short* xr = P.xcat + (size_t)b * 3072;
    const float* gt = P.gadec + (size_t)b * 2560 + d0;
#pragma unroll
    for (int j = 0; j < 8; ++j)
        xr[512 + d0 + j] = f2bf(sa[j] * gt[j]);

    int wword = P.caps[b * MAXLEN + t];
    for (int j = tid; j < 512; j += 256)
        xr[j] = f2bf(P.emb[(size_t)wword * 512 + j]);
}

// ---------------------------------------------------------------------------
// Phase B: gates partials  (all 256 blocks: 32 n-blocks x 8 K-slices)
// C = xcat[64x3072] @ WpL -> gparts[kz][64][2048]
// ---------------------------------------------------------------------------
__device__ __forceinline__ void gates_phase(const DecP& P)
{
    const int bx = blockIdx.x;
    const int nx = bx & 31, kz = bx >> 5;
    const int n0 = nx * 64;
    const unsigned short* A  = P.xcat + kz * 384;               // 12 kb * 32
    const unsigned short* Wp = P.WpL + (size_t)kz * 12 * 2048 * 32;
    float* C = P.gparts + (size_t)kz * BB * 2048;

    const int w  = threadIdx.x >> 6;
    const int l  = threadIdx.x & 63;
    const int lr = l & 15;
    const int q  = l >> 4;

    const unsigned short* ap = A + (size_t)(16 * w + lr) * 3072 + q * 8;
    const unsigned short* bp = Wp + (size_t)(n0 + lr) * 32 + q * 8;
    const size_t bstep = (size_t)2048 * 32;

    f32x4 acc[4];
#pragma unroll
    for (int i = 0; i < 4; ++i) acc[i] = (f32x4){0.f, 0.f, 0.f, 0.f};

    short8 a  = *(const short8*)ap;
    short8 b0 = *(const short8*)(bp);
    short8 b1 = *(const short8*)(bp + 512);
    short8 b2 = *(const short8*)(bp + 1024);
    short8 b3 = *(const short8*)(bp + 1536);

    for (int kb = 0; kb < 12; ++kb) {
        const size_t nxt = (kb + 1 < 12) ? 1 : 0;
        const unsigned short* apn = ap + nxt * 32;
        const unsigned short* bpn = bp + nxt * bstep;
        short8 an  = *(const short8*)apn;
        short8 bn0 = *(const short8*)(bpn);
        short8 bn1 = *(const short8*)(bpn + 512);
        short8 bn2 = *(const short8*)(bpn + 1024);
        short8 bn3 = *(const short8*)(bpn + 1536);
        acc[0] = __builtin_amdgcn_mfma_f32_16x16x32_bf16(a, b0, acc[0], 0, 0, 0);
        acc[1] = __builtin_amdgcn_mfma_f32_16x16x32_bf16(a, b1, acc[1], 0, 0, 0);
        acc[2] = __builtin_amdgcn_mfma_f32_16x16x32_bf16(a, b2, acc[2], 0, 0, 0);
        acc[3] = __builtin_amdgcn_mfma_f32_16x16x32_bf16(a, b3, acc[3], 0, 0, 0);
        a = an; b0 = bn0; b1 = bn1; b2 = bn2; b3 = bn3;
        ap = apn; bp = bpn;
    }

    const int r0 = q * 4;
#pragma unroll
    for (int cf = 0; cf < 4; ++cf) {
        int col = n0 + cf * 16 + lr;
#pragma unroll
        for (int r = 0; r < 4; ++r) {
            int row = 16 * w + r0 + r;
            C[(size_t)row * 2048 + col] = acc[cf][r];
        }
    }
}

// ---------------------------------------------------------------------------
// Phase C: LSTM reduce + gate math.  blocks 0..127
// ---------------------------------------------------------------------------
__device__ __forceinline__ void lstm_phase(const DecP& P, int t)
{
    int idx = blockIdx.x * 256 + threadIdx.x;  // 0..32767
    int b = idx >> 9, j = idx & 511;
    const float* g = P.gparts + (size_t)b * 2048;
    float gi = P.bsum[j],        gf = P.bsum[512 + j];
    float gg = P.bsum[1024 + j], go = P.bsum[1536 + j];
#pragma unroll
    for (int s = 0; s < 8; ++s) {
        const float* p = g + (size_t)s * BB * 2048;
        gi += p[j]; gf += p[512 + j]; gg += p[1024 + j]; go += p[1536 + j];
    }
    float cn = fsigm(gf) * P.c[idx] + fsigm(gi) * ftanh(gg);
    float hn = fsigm(go) * ftanh(cn);
    if (t < P.lens[b] - 1) {
        P.c[idx] = cn;
        P.xcat[(size_t)b * 3072 + 2560 + j] = f2bf(hn);
    }
}

// ---------------------------------------------------------------------------
// Phase D: fused output GEMM.  blocks 0..196 (or 157..196 for init)
//   cols [0,10000):      preds(t) -> out
//   cols [10048,12096):  gate     -> gadec[:, 0:2048]
//   cols [12096,12608):  adec     -> gadec[:, 2048:2560]
// ---------------------------------------------------------------------------
__device__ __forceinline__ void outgemm_phase(const DecP& P, int t)
{
    const int n0 = blockIdx.x * 64;
    const int w  = threadIdx.x >> 6;
    const int l  = threadIdx.x & 63;
    const int lr = l & 15;
    const int q  = l >> 4;

    const unsigned short* ap = P.xcat + 2560 + (size_t)(16 * w + lr) * 3072 + q * 8;
    const unsigned short* bp = P.WpO + (size_t)(n0 + lr) * 32 + q * 8;
    const size_t bstep = (size_t)NOUT * 32;

    f32x4 acc[4];
#pragma unroll
    for (int i = 0; i < 4; ++i) acc[i] = (f32x4){0.f, 0.f, 0.f, 0.f};

    short8 a  = *(const short8*)ap;
    short8 b0 = *(const short8*)(bp);
    short8 b1 = *(const short8*)(bp + 512);
    short8 b2 = *(const short8*)(bp + 1024);
    short8 b3 = *(const short8*)(bp + 1536);

    for (int kb = 0; kb < 16; ++kb) {
        const size_t nxt = (kb + 1 < 16) ? 1 : 0;
        const unsigned short* apn = ap + nxt * 32;
        const unsigned short* bpn = bp + nxt * bstep;
        short8 an  = *(const short8*)apn;
        short8 bn0 = *(const short8*)(bpn);
        short8 bn1 = *(const short8*)(bpn + 512);
        short8 bn2 = *(const short8*)(bpn + 1024);
        short8 bn3 = *(const short8*)(bpn + 1536);
        acc[0] = __builtin_amdgcn_mfma_f32_16x16x32_bf16(a, b0, acc[0], 0, 0, 0);
        acc[1] = __builtin_amdgcn_mfma_f32_16x16x32_bf16(a, b1, acc[1], 0, 0, 0);
        acc[2] = __builtin_amdgcn_mfma_f32_16x16x32_bf16(a, b2, acc[2], 0, 0, 0);
        acc[3] = __builtin_amdgcn_mfma_f32_16x16x32_bf16(a, b3, acc[3], 0, 0, 0);
        a = an; b0 = bn0; b1 = bn1; b2 = bn2; b3 = bn3;
        ap = apn; bp = bpn;
    }

    float* preds = P.out + (size_t)t * VOCAB_N;
    const int r0 = q * 4;
#pragma unroll
    for (int cf = 0; cf < 4; ++cf) {
        int col = n0 + cf * 16 + lr;
        float bv = P.bcat2[col];
#pragma unroll
        for (int r = 0; r < 4; ++r) {
            int row = 16 * w + r0 + r;
            float v = acc[cf][r] + bv;
            if (col < VOCAB_N) {
                float mk = (t < P.lens[row] - 1) ? 1.f : 0.f;
                preds[(size_t)row * ((size_t)TT * VOCAB_N) + col] = v * mk;
            } else if (col < 10048) {
                // padding
            } else if (col < 12096) {
                P.gadec[(size_t)row * 2560 + (col - 10048)] = fsigm(v);
            } else {
                P.gadec[(size_t)row * 2560 + 2048 + (col - 12096)] = v;
            }
        }
    }
}

// ---------------------------------------------------------------------------
// The cooperative decode loop: 256 blocks x 256 threads, 4 grid.sync per step
// ---------------------------------------------------------------------------
__global__ __launch_bounds__(256) void decode_loop(DecP P)
{
    cg::grid_group grid = cg::this_grid();
    const int bx = blockIdx.x;

    // init: gadec(0) from h0 (cols >= 10048 only -> no preds writes)
    if (bx >= 157 && bx < 197) outgemm_phase(P, 0);
    grid.sync();

    for (int t = 0; t < TT; ++t) {
        if (bx < 64) attawe_phase(P, t);
        grid.sync();
        gates_phase(P);
        grid.sync();
        if (bx < 128) lstm_phase(P, t);
        grid.sync();
        if (bx < 197) outgemm_phase(P, t);
        grid.sync();
    }
}

// ---------------------------------------------------------------------------
// Setup attenc GEMM: attenc16 = enc16 @ W_enc_att + b   (M=12544, N=512, K=2048)
// Block covers 2 m-tiles x 2 n-tiles (128x128), grid (4, 98) — 2x B reuse and
// 4x fewer B-panel re-reads vs the old (8,196) layout.
// ---------------------------------------------------------------------------
__global__ __launch_bounds__(256) void encatt_gemm(
    const unsigned short* __restrict__ A,
    const unsigned short* __restrict__ Wp,
    const float* __restrict__ bias,
    unsigned short* __restrict__ C16)
{
    const int n0 = blockIdx.x * 128;
    const int m0 = blockIdx.y * 128;
    const int w  = threadIdx.x >> 6;
    const int l  = threadIdx.x & 63;
    const int lr = l & 15;
    const int q  = l >> 4;

    const unsigned short* ap = A + (size_t)(m0 + 16 * w + lr) * 2048 + q * 8;
    const unsigned short* bp = Wp + (size_t)(n0 + lr) * 32 + q * 8;
    const size_t bstep = (size_t)512 * 32;

    f32x4 acc[16];
#pragma unroll
    for (int i = 0; i < 16; ++i) acc[i] = (f32x4){0.f, 0.f, 0.f, 0.f};

    short8 a0 = *(const short8*)(ap);
    short8 a1 = *(const short8*)(ap + 64 * 2048);
    short8 b[8];
#pragma unroll
    for (int nt = 0; nt < 8; ++nt) b[nt] = *(const short8*)(bp + nt * 512);

    for (int kb = 0; kb < 64; ++kb) {
        const size_t nxt = (kb + 1 < 64) ? 1 : 0;
        const unsigned short* apn = ap + nxt * 32;
        const unsigned short* bpn = bp + nxt * bstep;
        short8 an0 = *(const short8*)(apn);
        short8 an1 = *(const short8*)(apn + 64 * 2048);
        short8 bn[8];
#pragma unroll
        for (int nt = 0; nt < 8; ++nt) bn[nt] = *(const short8*)(bpn + nt * 512);
#pragma unroll
        for (int nt = 0; nt < 8; ++nt) {
            acc[nt]     = __builtin_amdgcn_mfma_f32_16x16x32_bf16(a0, b[nt], acc[nt], 0, 0, 0);
            acc[8 + nt] = __builtin_amdgcn_mfma_f32_16x16x32_bf16(a1, b[nt], acc[8 + nt], 0, 0, 0);
        }
        a0 = an0; a1 = an1;
#pragma unroll
        for (int nt = 0; nt < 8; ++nt) b[nt] = bn[nt];
        ap = apn; bp = bpn;
    }

    const int r0 = q * 4;
#pragma unroll
    for (int mt = 0; mt < 2; ++mt) {
#pragma unroll
        for (int nt = 0; nt < 8; ++nt) {
            int col = n0 + nt * 16 + lr;
            float bv = bias[col];
#pragma unroll
            for (int r = 0; r < 4; ++r) {
                int row = m0 + mt * 64 + 16 * w + r0 + r;
                C16[(size_t)row * 512 + col] = f2bf(acc[mt * 8 + nt][r] + bv);
            }
        }
    }
}

// ---------------------------------------------------------------------------
// Weight packing: Wp[(kb*Npad + n)*32 + kk] = src[k=kb*32+kk][n], bf16.
// mode 0: single source W1 (K x N1), pad n>=N1 with 0 (Npad >= N1)
// mode 2: k-concat [W1 (K1 x N1) ; W2 ((K-K1) x N1)], Npad = N1
// ---------------------------------------------------------------------------
__global__ void pack_kernel(const float* __restrict__ W1, const float* __restrict__ W2,
                            int N1, int N2, int K1, int Npad, int mode,
                            unsigned short* __restrict__ Wp, int total)
{
    int idx = blockIdx.x * 256 + threadIdx.x;
    if (idx >= total) return;
    int kk = idx & 31;
    int r  = idx >> 5;
    int n  = r % Npad;
    int kb = r / Npad;
    int k  = kb * 32 + kk;
    float v = 0.f;
    if (mode == 0) {
        if (n < N1) v = W1[(size_t)k * N1 + n];
    } else if (mode == 1) {
        v = (n < N1) ? W1[(size_t)k * N1 + n] : W2[(size_t)k * N2 + (n - N1)];
    } else {
        v = (k < K1) ? W1[(size_t)k * N1 + n] : W2[(size_t)(k - K1) * N1 + n];
    }
    Wp[idx] = f2bf(v);
}

// pack [W_fc(10000)+pad48 | W_fbeta(2048) | W_dec_att(512)], K=512, Npad=NOUT
__global__ void pack3_kernel(const float* __restrict__ Wfc,
                             const float* __restrict__ Wfb,
                             const float* __restrict__ Wda,
                             unsigned short* __restrict__ Wp, int total)
{
    int idx = blockIdx.x * 256 + threadIdx.x;
    if (idx >= total) return;
    int kk = idx & 31;
    int r  = idx >> 5;
    int n  = r % NOUT;
    int kb = r / NOUT;
    int k  = kb * 32 + kk;
    float v = 0.f;
    if (n < VOCAB_N)       v = Wfc[(size_t)k * VOCAB_N + n];
    else if (n < 10048)    v = 0.f;
    else if (n < 12096)    v = Wfb[(size_t)k * 2048 + (n - 10048)];
    else                   v = Wda[(size_t)k * 512 + (n - 12096)];
    Wp[idx] = f2bf(v);
}

__global__ void cast_kernel(const float* __restrict__ src,
                            unsigned short* __restrict__ dst, int n)
{
    int i = (blockIdx.x * 256 + threadIdx.x) * 4;
    if (i >= n) return;
    float4 v = *(const float4*)(src + i);
    dst[i]     = f2bf(v.x);
    dst[i + 1] = f2bf(v.y);
    dst[i + 2] = f2bf(v.z);
    dst[i + 3] = f2bf(v.w);
}

// bcat2[NOUT] = [b_fc | 0*48 | b_fbeta | b_dec_att]; bsum[2048] = b_ih + b_hh
__global__ void bias_prep(const float* __restrict__ bfc, const float* __restrict__ bfb,
                          const float* __restrict__ bda, const float* __restrict__ bih,
                          const float* __restrict__ bhh,
                          float* __restrict__ bcat2, float* __restrict__ bsum)
{
    int i = blockIdx.x * 256 + threadIdx.x;
    if (i < VOCAB_N) bcat2[i] = bfc[i];
    else if (i < 10048) bcat2[i] = 0.f;
    else if (i < 12096) bcat2[i] = bfb[i - 10048];
    else if (i < NOUT) bcat2[i] = bda[i - 12096];
    else if (i < NOUT + 2048) { int j = i - NOUT; bsum[j] = bih[j] + bhh[j]; }
}

__global__ void mean_kernel(const float* __restrict__ enc, float* __restrict__ me)
{
    int d = blockIdx.x * 256 + threadIdx.x;
    int b = blockIdx.y;
    const float* p = enc + (size_t)b * NPIX * ENCD + d;
    float s = 0.0f;
    for (int q = 0; q < NPIX; ++q) s += p[(size_t)q * ENCD];
    me[b * ENCD + d] = s * (1.0f / 196.0f);
}

// h0 (bf16 into xcat h-region) + c0 (fp32)
__global__ void inithc_kernel(const float* __restrict__ me,
                              const float* __restrict__ Wh, const float* __restrict__ bh,
                              const float* __restrict__ Wc, const float* __restrict__ bc,
                              unsigned short* __restrict__ xcat, float* __restrict__ c)
{
    int idx = blockIdx.x * 256 + threadIdx.x;  // 0..32767
    int b = idx >> 9, j = idx & 511;
    const float* m = me + b * ENCD;
    float sh = bh[j], sc = bc[j];
    for (int k = 0; k < ENCD; ++k) {
        float mv = m[k];
        sh += mv * Wh[(size_t)k * DECD + j];
        sc += mv * Wc[(size_t)k * DECD + j];
    }
    xcat[(size_t)b * 3072 + 2560 + j] = f2bf(sh);
    c[idx] = sc;
}

__global__ void copy_misc(const int* __restrict__ caps, const int* __restrict__ lens,
                          float* __restrict__ out)
{
    int i = blockIdx.x * 256 + threadIdx.x;
    if (i < CAPS_SZ) out[PRED_SZ + i] = (float)caps[i];
    else if (i < CAPS_SZ + LENS_SZ) out[PRED_SZ + i] = (float)(lens[i - CAPS_SZ] - 1);
}

// ---------------------------------------------------------------------------
extern "C" void kernel_launch(void* const* d_in, const int* in_sizes, int n_in,
                              void* d_out, int out_size, void* d_ws, size_t ws_size,
                              hipStream_t stream)
{
    (void)in_sizes; (void)n_in; (void)out_size; (void)ws_size;
    const float* enc        = (const float*)d_in[0];
    const int*   caps       = (const int*)d_in[1];
    const int*   lens       = (const int*)d_in[2];
    const float* emb        = (const float*)d_in[3];
    const float* W_enc_att  = (const float*)d_in[4];
    const float* b_enc_att  = (const float*)d_in[5];
    const float* W_dec_att  = (const float*)d_in[6];
    const float* b_dec_att  = (const float*)d_in[7];
    const float* W_full_att = (const float*)d_in[8];
    const float* b_full_att = (const float*)d_in[9];
    const float* W_init_h   = (const float*)d_in[10];
    const float* b_init_h   = (const float*)d_in[11];
    const float* W_init_c   = (const float*)d_in[12];
    const float* b_init_c   = (const float*)d_in[13];
    const float* W_fbeta    = (const float*)d_in[14];
    const float* b_fbeta    = (const float*)d_in[15];
    const float* W_ih       = (const float*)d_in[16];
    const float* W_hh       = (const float*)d_in[17];
    const float* b_ih       = (const float*)d_in[18];
    const float* b_hh       = (const float*)d_in[19];
    const float* W_fc       = (const float*)d_in[20];
    const float* b_fc       = (const float*)d_in[21];
    float* out = (float*)d_out;

    // ---- workspace carve-up (16B aligned chunks) ----
    char* p = (char*)d_ws;
    unsigned short* enc16   = (unsigned short*)p; p += (size_t)BB * NPIX * ENCD * 2;   // 51.4MB
    unsigned short* attenc16= (unsigned short*)p; p += (size_t)BB * NPIX * 512 * 2;    // 12.8MB
    unsigned short* WpL     = (unsigned short*)p; p += (size_t)96 * 2048 * 32 * 2;     // 12.6MB gates K=3072 Npad=2048
    unsigned short* WpO     = (unsigned short*)p; p += (size_t)16 * NOUT * 32 * 2;     // 12.9MB fc|fbeta|dec_att K=512
    unsigned short* WpE     = (unsigned short*)p; p += (size_t)64 * 512 * 32 * 2;      // 2.1MB  enc_att K=2048 Npad=512
    unsigned short* xcat    = (unsigned short*)p; p += (size_t)BB * 3072 * 2;          // 384KB
    float* gadec  = (float*)p; p += (size_t)BB * 2560 * 4;                             // 640KB
    float* gparts = (float*)p; p += (size_t)8 * BB * 2048 * 4;                         // 4MB
    float* c      = (float*)p; p += (size_t)BB * 512 * 4;                              // 128KB
    float* me     = (float*)p; p += (size_t)BB * ENCD * 4;                             // 512KB
    float* bcat2  = (float*)p; p += NOUT * 4;
    float* bsum   = (float*)p; p += 2048 * 4;

    // ---- setup ----
    {
        int n = BB * NPIX * ENCD;
        cast_kernel<<<(n / 4 + 255) / 256, 256, 0, stream>>>(enc, enc16, n);
    }
    { int tot = 96 * 2048 * 32;
      pack_kernel<<<(tot + 255) / 256, 256, 0, stream>>>(W_ih, W_hh, 2048, 2048, 2560, 2048, 2, WpL, tot); }
    { int tot = 16 * NOUT * 32;
      pack3_kernel<<<(tot + 255) / 256, 256, 0, stream>>>(W_fc, W_fbeta, W_dec_att, WpO, tot); }
    { int tot = 64 * 512 * 32;
      pack_kernel<<<(tot + 255) / 256, 256, 0, stream>>>(W_enc_att, nullptr, 512, 0, 0, 512, 0, WpE, tot); }
    bias_prep<<<(NOUT + 2048 + 255) / 256, 256, 0, stream>>>(b_fc, b_fbeta, b_dec_att, b_ih, b_hh, bcat2, bsum);
    mean_kernel<<<dim3(8, 64), 256, 0, stream>>>(enc, me);
    inithc_kernel<<<128, 256, 0, stream>>>(me, W_init_h, b_init_h, W_init_c, b_init_c, xcat, c);
    encatt_gemm<<<dim3(4, 98), 256, 0, stream>>>(enc16, WpE, b_enc_att, attenc16);
    copy_misc<<<14, 256, 0, stream>>>(caps, lens, out);

    // ---- cooperative decode loop ----
    DecP P;
    P.attenc16 = attenc16;
    P.enc16    = enc16;
    P.xcat     = xcat;
    P.gadec    = gadec;
    P.gparts   = gparts;
    P.c        = c;
    P.Wf       = W_full_att;
    P.bfull    = b_full_att;
    P.emb      = emb;
    P.caps     = caps;
    P.lens     = lens;
    P.WpL      = WpL;
    P.WpO      = WpO;
    P.bcat2    = bcat2;
    P.bsum     = bsum;
    P.out      = out;

    void* args[] = { &P };
    hipLaunchCooperativeKernel(reinterpret_cast<void*>(decode_loop),
                               dim3(256), dim3(256), args, 0, stream);
}

// Round 3
// 5033.599 us; speedup vs baseline: 2.3847x; 2.3847x over previous
//
#include <hip/hip_runtime.h>
#include <hip/hip_bf16.h>
#include <math.h>

#define BB 64
#define NPIX 196
#define ENCD 2048
#define DECD 512
#define VOCAB_N 10000
#define MAXLEN 52
#define TT 51
#define NPADFC 10048

// Output layout (floats): preds | captions | declens | alphas
#define PRED_SZ   (BB * TT * VOCAB_N)
#define CAPS_SZ   (BB * MAXLEN)
#define LENS_SZ   (BB)
#define ALPHAS_OFF (PRED_SZ + CAPS_SZ + LENS_SZ)

typedef __attribute__((ext_vector_type(8))) short short8;
typedef __attribute__((ext_vector_type(4))) float f32x4;

__device__ __forceinline__ float fsigm(float x) {
    return 1.0f / (1.0f + __expf(-x));
}
__device__ __forceinline__ float ftanh(float x) {
    x = fminf(fmaxf(x, -15.0f), 15.0f);
    float e = __expf(2.0f * x);
    return (e - 1.0f) / (e + 1.0f);
}
__device__ __forceinline__ float bf2f(unsigned short u) {
    union { unsigned int i; float f; } v;
    v.i = ((unsigned int)u) << 16;
    return v.f;
}
__device__ __forceinline__ unsigned short f2bf(float f) {
    union { float f; unsigned int i; } v;
    v.f = f;
    unsigned int r = v.i + 0x7FFFu + ((v.i >> 16) & 1u);
    return (unsigned short)(r >> 16);
}

// ---------------------------------------------------------------------------
// Generic MFMA GEMM (verified round-0/1 path). Used for the in-loop gadec
// GEMM: gadec = [sigmoid(h@Wfbeta+b) | h@Wd+bd], 40 blocks, act=2.
// ---------------------------------------------------------------------------
__global__ __launch_bounds__(256) void gemm_mfma(
    const unsigned short* __restrict__ A, int lda,
    const unsigned short* __restrict__ Wp, int Npad,
    int nkb, long slice_stride,
    float* __restrict__ C, unsigned short* __restrict__ C16, long ldc,
    const float* __restrict__ bias, int N, int act,
    const int* __restrict__ caplen, int t)
{
    const int n0 = blockIdx.x * 64;
    const int m0 = blockIdx.y * 64;
    const int kz = blockIdx.z;
    A  += (size_t)kz * nkb * 32;
    Wp += (size_t)kz * nkb * Npad * 32;
    if (C) C += (size_t)kz * slice_stride;

    const int w  = threadIdx.x >> 6;
    const int l  = threadIdx.x & 63;
    const int lr = l & 15;
    const int q  = l >> 4;

    const unsigned short* ap = A + (size_t)(m0 + 16 * w + lr) * lda + q * 8;
    const unsigned short* bp = Wp + (size_t)(n0 + lr) * 32 + q * 8;
    const size_t bstep = (size_t)Npad * 32;

    f32x4 acc[4];
#pragma unroll
    for (int i = 0; i < 4; ++i) acc[i] = (f32x4){0.f, 0.f, 0.f, 0.f};

    short8 a  = *(const short8*)ap;
    short8 b0 = *(const short8*)(bp);
    short8 b1 = *(const short8*)(bp + 512);
    short8 b2 = *(const short8*)(bp + 1024);
    short8 b3 = *(const short8*)(bp + 1536);

    for (int kb = 0; kb < nkb; ++kb) {
        const size_t nxt = (kb + 1 < nkb) ? 1 : 0;
        const unsigned short* apn = ap + nxt * 32;
        const unsigned short* bpn = bp + nxt * bstep;
        short8 an  = *(const short8*)apn;
        short8 bn0 = *(const short8*)(bpn);
        short8 bn1 = *(const short8*)(bpn + 512);
        short8 bn2 = *(const short8*)(bpn + 1024);
        short8 bn3 = *(const short8*)(bpn + 1536);
        acc[0] = __builtin_amdgcn_mfma_f32_16x16x32_bf16(a, b0, acc[0], 0, 0, 0);
        acc[1] = __builtin_amdgcn_mfma_f32_16x16x32_bf16(a, b1, acc[1], 0, 0, 0);
        acc[2] = __builtin_amdgcn_mfma_f32_16x16x32_bf16(a, b2, acc[2], 0, 0, 0);
        acc[3] = __builtin_amdgcn_mfma_f32_16x16x32_bf16(a, b3, acc[3], 0, 0, 0);
        a = an; b0 = bn0; b1 = bn1; b2 = bn2; b3 = bn3;
        ap = apn; bp = bpn;
    }

    const int r0 = q * 4;
#pragma unroll
    for (int cf = 0; cf < 4; ++cf) {
        int col = n0 + cf * 16 + lr;
        if (col >= N) continue;
        float bv = bias ? bias[col] : 0.f;
#pragma unroll
        for (int r = 0; r < 4; ++r) {
            int row = m0 + 16 * w + r0 + r;
            float v = acc[cf][r] + bv;
            if (act == 1 || (act == 2 && col < 2048)) v = fsigm(v);
            if (caplen) v *= (t < caplen[row] - 1) ? 1.f : 0.f;
            if (C16) C16[(size_t)row * ldc + col] = f2bf(v);
            else     C [(size_t)row * ldc + col] = v;
        }
    }
}

// ---------------------------------------------------------------------------
// Fused gates GEMM + LSTM. 32 blocks x 512 threads (8 waves = 2 K-slices).
// WpLi is gate-interleaved: packed col 4*j+g = original col g*512+j of
// [W_ih; W_hh] (K=3072). Block bx covers packed cols bx*64..+63 = units
// j0..j0+15, all 4 gates. Epilogue: LDS tile -> LSTM math -> c, xcat.h, hhist.
// ---------------------------------------------------------------------------
__global__ __launch_bounds__(512) void gates_lstm_kernel(
    unsigned short* __restrict__ xcat,
    const unsigned short* __restrict__ WpLi,
    const float* __restrict__ bsum,
    const int* __restrict__ caplen, int t,
    float* __restrict__ c,
    unsigned short* __restrict__ hhist)
{
    __shared__ float gt[2][64][68];

    const int n0 = blockIdx.x * 64;
    const int j0 = blockIdx.x * 16;
    const int tid = threadIdx.x;
    const int ws = tid >> 8;           // K-slice 0/1 (48 k-blocks each)
    const int w  = (tid >> 6) & 3;
    const int l  = tid & 63;
    const int lr = l & 15;
    const int q  = l >> 4;

    const unsigned short* A  = xcat + ws * 1536;   // 48 kb * 32 elems
    const unsigned short* Wp = WpLi + (size_t)ws * 48 * 2048 * 32;

    const unsigned short* ap = A + (size_t)(16 * w + lr) * 3072 + q * 8;
    const unsigned short* bp = Wp + (size_t)(n0 + lr) * 32 + q * 8;
    const size_t bstep = (size_t)2048 * 32;

    f32x4 acc[4];
#pragma unroll
    for (int i = 0; i < 4; ++i) acc[i] = (f32x4){0.f, 0.f, 0.f, 0.f};

    short8 a  = *(const short8*)ap;
    short8 b0 = *(const short8*)(bp);
    short8 b1 = *(const short8*)(bp + 512);
    short8 b2 = *(const short8*)(bp + 1024);
    short8 b3 = *(const short8*)(bp + 1536);

    for (int kb = 0; kb < 48; ++kb) {
        const size_t nxt = (kb + 1 < 48) ? 1 : 0;
        const unsigned short* apn = ap + nxt * 32;
        const unsigned short* bpn = bp + nxt * bstep;
        short8 an  = *(const short8*)apn;
        short8 bn0 = *(const short8*)(bpn);
        short8 bn1 = *(const short8*)(bpn + 512);
        short8 bn2 = *(const short8*)(bpn + 1024);
        short8 bn3 = *(const short8*)(bpn + 1536);
        acc[0] = __builtin_amdgcn_mfma_f32_16x16x32_bf16(a, b0, acc[0], 0, 0, 0);
        acc[1] = __builtin_amdgcn_mfma_f32_16x16x32_bf16(a, b1, acc[1], 0, 0, 0);
        acc[2] = __builtin_amdgcn_mfma_f32_16x16x32_bf16(a, b2, acc[2], 0, 0, 0);
        acc[3] = __builtin_amdgcn_mfma_f32_16x16x32_bf16(a, b3, acc[3], 0, 0, 0);
        a = an; b0 = bn0; b1 = bn1; b2 = bn2; b3 = bn3;
        ap = apn; bp = bpn;
    }

    const int r0 = q * 4;
#pragma unroll
    for (int cf = 0; cf < 4; ++cf) {
#pragma unroll
        for (int r = 0; r < 4; ++r)
            gt[ws][16 * w + r0 + r][cf * 16 + lr] = acc[cf][r];
    }
    __syncthreads();

    // LSTM epilogue: 1024 (row, unit) items over 512 threads
#pragma unroll
    for (int it = 0; it < 2; ++it) {
        int item = tid + 512 * it;
        int row = item & 63;
        int jj  = item >> 6;      // 0..15
        int j   = j0 + jj;
        int lc  = 4 * jj;
        float gi = gt[0][row][lc + 0] + gt[1][row][lc + 0] + bsum[j];
        float gf = gt[0][row][lc + 1] + gt[1][row][lc + 1] + bsum[512 + j];
        float gg = gt[0][row][lc + 2] + gt[1][row][lc + 2] + bsum[1024 + j];
        float go = gt[0][row][lc + 3] + gt[1][row][lc + 3] + bsum[1536 + j];
        int cidx = row * 512 + j;
        float cn = fsigm(gf) * c[cidx] + fsigm(gi) * ftanh(gg);
        float hn = fsigm(go) * ftanh(cn);
        unsigned short* hx = xcat + (size_t)row * 3072 + 2560 + j;
        unsigned short oldh = *hx;
        bool upd = (t < caplen[row] - 1);
        unsigned short hv = upd ? f2bf(hn) : oldh;
        if (upd) { c[cidx] = cn; *hx = hv; }
        hhist[((size_t)t * BB + row) * 512 + j] = hv;
    }
}

// ---------------------------------------------------------------------------
// Final preds GEMM over the whole h history: rows = t*64+b (3264), K=512.
// preds[b][t][col] = (h(t) @ W_fc + b_fc) * (t < caplen[b]-1)
// ---------------------------------------------------------------------------
__global__ __launch_bounds__(256) void preds_gemm(
    const unsigned short* __restrict__ hhist,
    const unsigned short* __restrict__ WpF,
    const float* __restrict__ bfc,
    const int* __restrict__ caplen,
    float* __restrict__ out)
{
    const int n0 = blockIdx.x * 64;
    const int row0 = blockIdx.y * 64;
    const int w  = threadIdx.x >> 6;
    const int l  = threadIdx.x & 63;
    const int lr = l & 15;
    const int q  = l >> 4;

    const unsigned short* ap = hhist + (size_t)(row0 + 16 * w + lr) * 512 + q * 8;
    const unsigned short* bp = WpF + (size_t)(n0 + lr) * 32 + q * 8;
    const size_t bstep = (size_t)NPADFC * 32;

    f32x4 acc[4];
#pragma unroll
    for (int i = 0; i < 4; ++i) acc[i] = (f32x4){0.f, 0.f, 0.f, 0.f};

    short8 a  = *(const short8*)ap;
    short8 b0 = *(const short8*)(bp);
    short8 b1 = *(const short8*)(bp + 512);
    short8 b2 = *(const short8*)(bp + 1024);
    short8 b3 = *(const short8*)(bp + 1536);

    for (int kb = 0; kb < 16; ++kb) {
        const size_t nxt = (kb + 1 < 16) ? 1 : 0;
        const unsigned short* apn = ap + nxt * 32;
        const unsigned short* bpn = bp + nxt * bstep;
        short8 an  = *(const short8*)apn;
        short8 bn0 = *(const short8*)(bpn);
        short8 bn1 = *(const short8*)(bpn + 512);
        short8 bn2 = *(const short8*)(bpn + 1024);
        short8 bn3 = *(const short8*)(bpn + 1536);
        acc[0] = __builtin_amdgcn_mfma_f32_16x16x32_bf16(a, b0, acc[0], 0, 0, 0);
        acc[1] = __builtin_amdgcn_mfma_f32_16x16x32_bf16(a, b1, acc[1], 0, 0, 0);
        acc[2] = __builtin_amdgcn_mfma_f32_16x16x32_bf16(a, b2, acc[2], 0, 0, 0);
        acc[3] = __builtin_amdgcn_mfma_f32_16x16x32_bf16(a, b3, acc[3], 0, 0, 0);
        a = an; b0 = bn0; b1 = bn1; b2 = bn2; b3 = bn3;
        ap = apn; bp = bpn;
    }

    const int r0 = q * 4;
#pragma unroll
    for (int cf = 0; cf < 4; ++cf) {
        int col = n0 + cf * 16 + lr;
        if (col >= VOCAB_N) continue;
        float bv = bfc[col];
#pragma unroll
        for (int r = 0; r < 4; ++r) {
            int row = row0 + 16 * w + r0 + r;
            int tt = row >> 6, b = row & 63;
            float mk = (tt < caplen[b] - 1) ? 1.f : 0.f;
            out[((size_t)b * TT + tt) * VOCAB_N + col] = (acc[cf][r] + bv) * mk;
        }
    }
}

// ---------------------------------------------------------------------------
// Weight packing: Wp[(kb*Npad + n)*32 + kk] = src[k=kb*32+kk][n], bf16.
// mode 0: single source W1 (K x N1), pad n>=N1 with 0 (Npad >= N1)
// mode 1: n-concat [W1 (K x N1) | W2 (K x N2)], Npad = N1+N2
// ---------------------------------------------------------------------------
__global__ void pack_kernel(const float* __restrict__ W1, const float* __restrict__ W2,
                            int N1, int N2, int K1, int Npad, int mode,
                            unsigned short* __restrict__ Wp, int total)
{
    int idx = blockIdx.x * 256 + threadIdx.x;
    if (idx >= total) return;
    int kk = idx & 31;
    int r  = idx >> 5;
    int n  = r % Npad;
    int kb = r / Npad;
    int k  = kb * 32 + kk;
    float v = 0.f;
    if (mode == 0) {
        if (n < N1) v = W1[(size_t)k * N1 + n];
    } else if (mode == 1) {
        v = (n < N1) ? W1[(size_t)k * N1 + n] : W2[(size_t)k * N2 + (n - N1)];
    } else {
        v = (k < K1) ? W1[(size_t)k * N1 + n] : W2[(size_t)(k - K1) * N1 + n];
    }
    Wp[idx] = f2bf(v);
}

// gate-interleaved pack of [W_ih(2560x2048); W_hh(512x2048)]:
// packed col n -> original col (n&3)*512 + (n>>2)
__global__ void packGi_kernel(const float* __restrict__ Wih,
                              const float* __restrict__ Whh,
                              unsigned short* __restrict__ Wp, int total)
{
    int idx = blockIdx.x * 256 + threadIdx.x;
    if (idx >= total) return;
    int kk = idx & 31;
    int r  = idx >> 5;
    int n  = r % 2048;
    int kb = r / 2048;
    int k  = kb * 32 + kk;
    int oc = (n & 3) * 512 + (n >> 2);
    float v = (k < 2560) ? Wih[(size_t)k * 2048 + oc]
                         : Whh[(size_t)(k - 2560) * 2048 + oc];
    Wp[idx] = f2bf(v);
}

__global__ void cast_kernel(const float* __restrict__ src,
                            unsigned short* __restrict__ dst, int n)
{
    int i = (blockIdx.x * 256 + threadIdx.x) * 4;
    if (i >= n) return;
    float4 v = *(const float4*)(src + i);
    dst[i]     = f2bf(v.x);
    dst[i + 1] = f2bf(v.y);
    dst[i + 2] = f2bf(v.z);
    dst[i + 3] = f2bf(v.w);
}

// bcat[2560] = [b_fbeta | b_dec_att]; bsum[2048] = b_ih + b_hh
__global__ void bias_prep(const float* __restrict__ bfb, const float* __restrict__ bda,
                          const float* __restrict__ bih, const float* __restrict__ bhh,
                          float* __restrict__ bcat, float* __restrict__ bsum)
{
    int i = blockIdx.x * 256 + threadIdx.x;
    if (i < 2048) bcat[i] = bfb[i];
    else if (i < 2560) bcat[i] = bda[i - 2048];
    else if (i < 2560 + 2048) { int j = i - 2560; bsum[j] = bih[j] + bhh[j]; }
}

__global__ void mean_kernel(const float* __restrict__ enc, float* __restrict__ me)
{
    int d = blockIdx.x * 256 + threadIdx.x;
    int b = blockIdx.y;
    const float* p = enc + (size_t)b * NPIX * ENCD + d;
    float s = 0.0f;
    for (int q = 0; q < NPIX; ++q) s += p[(size_t)q * ENCD];
    me[b * ENCD + d] = s * (1.0f / 196.0f);
}

// h0 (bf16 into xcat h-region) + c0 (fp32)
__global__ void inithc_kernel(const float* __restrict__ me,
                              const float* __restrict__ Wh, const float* __restrict__ bh,
                              const float* __restrict__ Wc, const float* __restrict__ bc,
                              unsigned short* __restrict__ xcat, float* __restrict__ c)
{
    int idx = blockIdx.x * 256 + threadIdx.x;  // 0..32767
    int b = idx >> 9, j = idx & 511;
    const float* m = me + b * ENCD;
    float sh = bh[j], sc = bc[j];
    for (int k = 0; k < ENCD; ++k) {
        float mv = m[k];
        sh += mv * Wh[(size_t)k * DECD + j];
        sc += mv * Wc[(size_t)k * DECD + j];
    }
    xcat[(size_t)b * 3072 + 2560 + j] = f2bf(sh);
    c[idx] = sc;
}

__global__ void copy_misc(const int* __restrict__ caps, const int* __restrict__ lens,
                          float* __restrict__ out)
{
    int i = blockIdx.x * 256 + threadIdx.x;
    if (i < CAPS_SZ) out[PRED_SZ + i] = (float)caps[i];
    else if (i < CAPS_SZ + LENS_SZ) out[PRED_SZ + i] = (float)(lens[i - CAPS_SZ] - 1);
}

// ---------------------------------------------------------------------------
// Fused attention + awe + xcat build (verified round-1). One 512-thread block
// per batch row.
// ---------------------------------------------------------------------------
__global__ __launch_bounds__(512) void attawe_kernel(
    const float* __restrict__ gadec,
    const unsigned short* __restrict__ attenc16,
    const unsigned short* __restrict__ enc16,
    const float* __restrict__ Wf, const float* __restrict__ bf_,
    const float* __restrict__ emb, const int* __restrict__ caps,
    const int* __restrict__ caplen, int t,
    unsigned short* __restrict__ xcat,
    float* __restrict__ alphas_out)
{
    int b = blockIdx.x;
    int tid = threadIdx.x;
    int lane = tid & 63, wid = tid >> 6;
    __shared__ float av[512];
    __shared__ float wv[512];
    __shared__ float es[NPIX];
    __shared__ float alpha_s[NPIX];
    __shared__ float r8[8];
    __shared__ float smax, ssum;

    av[tid] = gadec[(size_t)b * 2560 + 2048 + tid];
    wv[tid] = Wf[tid];
    __syncthreads();

    float mya[8], myw[8];
#pragma unroll
    for (int i = 0; i < 8; ++i) {
        mya[i] = av[lane * 8 + i];
        myw[i] = wv[lane * 8 + i];
    }

    float bf0 = bf_[0];
    for (int p = wid; p < NPIX; p += 8) {
        const unsigned short* ae = attenc16 + ((size_t)(b * NPIX + p)) * 512 + lane * 8;
        short8 e8 = *(const short8*)ae;
        float s = 0.f;
#pragma unroll
        for (int i = 0; i < 8; ++i)
            s += ftanh(bf2f((unsigned short)e8[i]) + mya[i]) * myw[i];
        for (int off = 32; off; off >>= 1) s += __shfl_down(s, off);
        if (lane == 0) es[p] = s + bf0;
    }
    __syncthreads();

    float v = (tid < NPIX) ? es[tid] : -1e30f;
    float m = v;
    for (int off = 32; off; off >>= 1) m = fmaxf(m, __shfl_down(m, off));
    if (lane == 0) r8[wid] = m;
    __syncthreads();
    if (tid == 0) {
        float mm = r8[0];
#pragma unroll
        for (int i = 1; i < 8; ++i) mm = fmaxf(mm, r8[i]);
        smax = mm;
    }
    __syncthreads();

    float ev = (tid < NPIX) ? __expf(v - smax) : 0.0f;
    float s = ev;
    for (int off = 32; off; off >>= 1) s += __shfl_down(s, off);
    if (lane == 0) r8[wid] = s;
    __syncthreads();
    if (tid == 0) {
        float ss = 0.f;
#pragma unroll
        for (int i = 0; i < 8; ++i) ss += r8[i];
        ssum = ss;
    }
    __syncthreads();

    float mk = (t < caplen[b] - 1) ? 1.0f : 0.0f;
    if (tid < NPIX) {
        float a = ev / ssum;
        alpha_s[tid] = a;
        alphas_out[((size_t)b * TT + t) * NPIX + tid] = a * mk;
    }
    __syncthreads();

    // awe: 4 d's per thread (512*4 = 2048)
    int d0 = tid * 4;
    const unsigned short* e = enc16 + (size_t)b * NPIX * ENCD + d0;
    float s0 = 0.f, s1 = 0.f, s2 = 0.f, s3 = 0.f;
    typedef __attribute__((ext_vector_type(4))) short short4v;
    for (int p = 0; p < NPIX; ++p) {
        short4v v4 = *(const short4v*)(e + (size_t)p * ENCD);
        float a = alpha_s[p];
        s0 += a * bf2f((unsigned short)v4[0]);
        s1 += a * bf2f((unsigned short)v4[1]);
        s2 += a * bf2f((unsigned short)v4[2]);
        s3 += a * bf2f((unsigned short)v4[3]);
    }
    unsigned short* xr = xcat + (size_t)b * 3072;
    const float* gt = gadec + (size_t)b * 2560 + d0;
    xr[512 + d0 + 0] = f2bf(s0 * gt[0]);
    xr[512 + d0 + 1] = f2bf(s1 * gt[1]);
    xr[512 + d0 + 2] = f2bf(s2 * gt[2]);
    xr[512 + d0 + 3] = f2bf(s3 * gt[3]);

    int wword = caps[b * MAXLEN + t];
    xr[tid] = f2bf(emb[(size_t)wword * 512 + tid]);
}

// ---------------------------------------------------------------------------
// Setup attenc GEMM: attenc16 = enc16 @ W_enc_att + b  (M=12544, N=512, K=2048)
// 128x128 tiles, grid (4, 98).
// ---------------------------------------------------------------------------
__global__ __launch_bounds__(256) void encatt_gemm(
    const unsigned short* __restrict__ A,
    const unsigned short* __restrict__ Wp,
    const float* __restrict__ bias,
    unsigned short* __restrict__ C16)
{
    const int n0 = blockIdx.x * 128;
    const int m0 = blockIdx.y * 128;
    const int w  = threadIdx.x >> 6;
    const int l  = threadIdx.x & 63;
    const int lr = l & 15;
    const int q  = l >> 4;

    const unsigned short* ap = A + (size_t)(m0 + 16 * w + lr) * 2048 + q * 8;
    const unsigned short* bp = Wp + (size_t)(n0 + lr) * 32 + q * 8;
    const size_t bstep = (size_t)512 * 32;

    f32x4 acc[16];
#pragma unroll
    for (int i = 0; i < 16; ++i) acc[i] = (f32x4){0.f, 0.f, 0.f, 0.f};

    short8 a0 = *(const short8*)(ap);
    short8 a1 = *(const short8*)(ap + 64 * 2048);
    short8 b[8];
#pragma unroll
    for (int nt = 0; nt < 8; ++nt) b[nt] = *(const short8*)(bp + nt * 512);

    for (int kb = 0; kb < 64; ++kb) {
        const size_t nxt = (kb + 1 < 64) ? 1 : 0;
        const unsigned short* apn = ap + nxt * 32;
        const unsigned short* bpn = bp + nxt * bstep;
        short8 an0 = *(const short8*)(apn);
        short8 an1 = *(const short8*)(apn + 64 * 2048);
        short8 bn[8];
#pragma unroll
        for (int nt = 0; nt < 8; ++nt) bn[nt] = *(const short8*)(bpn + nt * 512);
#pragma unroll
        for (int nt = 0; nt < 8; ++nt) {
            acc[nt]     = __builtin_amdgcn_mfma_f32_16x16x32_bf16(a0, b[nt], acc[nt], 0, 0, 0);
            acc[8 + nt] = __builtin_amdgcn_mfma_f32_16x16x32_bf16(a1, b[nt], acc[8 + nt], 0, 0, 0);
        }
        a0 = an0; a1 = an1;
#pragma unroll
        for (int nt = 0; nt < 8; ++nt) b[nt] = bn[nt];
        ap = apn; bp = bpn;
    }

    const int r0 = q * 4;
#pragma unroll
    for (int mt = 0; mt < 2; ++mt) {
#pragma unroll
        for (int nt = 0; nt < 8; ++nt) {
            int col = n0 + nt * 16 + lr;
            float bv = bias[col];
#pragma unroll
            for (int r = 0; r < 4; ++r) {
                int row = m0 + mt * 64 + 16 * w + r0 + r;
                C16[(size_t)row * 512 + col] = f2bf(acc[mt * 8 + nt][r] + bv);
            }
        }
    }
}

// ---------------------------------------------------------------------------
extern "C" void kernel_launch(void* const* d_in, const int* in_sizes, int n_in,
                              void* d_out, int out_size, void* d_ws, size_t ws_size,
                              hipStream_t stream)
{
    (void)in_sizes; (void)n_in; (void)out_size; (void)ws_size;
    const float* enc        = (const float*)d_in[0];
    const int*   caps       = (const int*)d_in[1];
    const int*   lens       = (const int*)d_in[2];
    const float* emb        = (const float*)d_in[3];
    const float* W_enc_att  = (const float*)d_in[4];
    const float* b_enc_att  = (const float*)d_in[5];
    const float* W_dec_att  = (const float*)d_in[6];
    const float* b_dec_att  = (const float*)d_in[7];
    const float* W_full_att = (const float*)d_in[8];
    const float* b_full_att = (const float*)d_in[9];
    const float* W_init_h   = (const float*)d_in[10];
    const float* b_init_h   = (const float*)d_in[11];
    const float* W_init_c   = (const float*)d_in[12];
    const float* b_init_c   = (const float*)d_in[13];
    const float* W_fbeta    = (const float*)d_in[14];
    const float* b_fbeta    = (const float*)d_in[15];
    const float* W_ih       = (const float*)d_in[16];
    const float* W_hh       = (const float*)d_in[17];
    const float* b_ih       = (const float*)d_in[18];
    const float* b_hh       = (const float*)d_in[19];
    const float* W_fc       = (const float*)d_in[20];
    const float* b_fc       = (const float*)d_in[21];
    float* out = (float*)d_out;

    // ---- workspace carve-up (16B aligned chunks) ----
    char* p = (char*)d_ws;
    unsigned short* enc16   = (unsigned short*)p; p += (size_t)BB * NPIX * ENCD * 2;   // 51.4MB
    unsigned short* attenc16= (unsigned short*)p; p += (size_t)BB * NPIX * 512 * 2;    // 12.8MB
    unsigned short* WpLi    = (unsigned short*)p; p += (size_t)96 * 2048 * 32 * 2;     // 12.6MB gates (interleaved) K=3072
    unsigned short* WpG     = (unsigned short*)p; p += (size_t)16 * 2560 * 32 * 2;     // 2.6MB  fbeta|dec_att K=512
    unsigned short* WpF     = (unsigned short*)p; p += (size_t)16 * NPADFC * 32 * 2;   // 10.3MB fc K=512
    unsigned short* WpE     = (unsigned short*)p; p += (size_t)64 * 512 * 32 * 2;      // 2.1MB  enc_att K=2048
    unsigned short* xcat    = (unsigned short*)p; p += (size_t)BB * 3072 * 2;          // 384KB
    unsigned short* hhist   = (unsigned short*)p; p += (size_t)TT * BB * 512 * 2;      // 3.3MB
    float* gadec  = (float*)p; p += (size_t)BB * 2560 * 4;                             // 640KB
    float* c      = (float*)p; p += (size_t)BB * 512 * 4;                              // 128KB
    float* me     = (float*)p; p += (size_t)BB * ENCD * 4;                             // 512KB
    float* bcat   = (float*)p; p += 2560 * 4;
    float* bsum   = (float*)p; p += 2048 * 4;

    // ---- setup ----
    {
        int n = BB * NPIX * ENCD;
        cast_kernel<<<(n / 4 + 255) / 256, 256, 0, stream>>>(enc, enc16, n);
    }
    { int tot = 96 * 2048 * 32;
      packGi_kernel<<<(tot + 255) / 256, 256, 0, stream>>>(W_ih, W_hh, WpLi, tot); }
    { int tot = 16 * 2560 * 32;
      pack_kernel<<<(tot + 255) / 256, 256, 0, stream>>>(W_fbeta, W_dec_att, 2048, 512, 0, 2560, 1, WpG, tot); }
    { int tot = 16 * NPADFC * 32;
      pack_kernel<<<(tot + 255) / 256, 256, 0, stream>>>(W_fc, nullptr, VOCAB_N, 0, 0, NPADFC, 0, WpF, tot); }
    { int tot = 64 * 512 * 32;
      pack_kernel<<<(tot + 255) / 256, 256, 0, stream>>>(W_enc_att, nullptr, 512, 0, 0, 512, 0, WpE, tot); }
    bias_prep<<<18, 256, 0, stream>>>(b_fbeta, b_dec_att, b_ih, b_hh, bcat, bsum);
    mean_kernel<<<dim3(8, 64), 256, 0, stream>>>(enc, me);
    inithc_kernel<<<128, 256, 0, stream>>>(me, W_init_h, b_init_h, W_init_c, b_init_c, xcat, c);
    encatt_gemm<<<dim3(4, 98), 256, 0, stream>>>(enc16, WpE, b_enc_att, attenc16);
    copy_misc<<<14, 256, 0, stream>>>(caps, lens, out);

    const unsigned short* h16 = xcat + 2560;  // lda = 3072

    // gadec(0) = [sigmoid(h0@Wfbeta+b) | h0@Wd+bd]
    gemm_mfma<<<dim3(40, 1, 1), 256, 0, stream>>>(
        h16, 3072, WpG, 2560, 16, 0, gadec, nullptr, 2560,
        bcat, 2560, 2, nullptr, 0);

    // ---- decode loop: 3 kernels/step ----
    for (int t = 0; t < TT; ++t) {
        attawe_kernel<<<64, 512, 0, stream>>>(
            gadec, attenc16, enc16, W_full_att, b_full_att,
            emb, caps, lens, t, xcat, out + ALPHAS_OFF);
        gates_lstm_kernel<<<32, 512, 0, stream>>>(
            xcat, WpLi, bsum, lens, t, c, hhist);
        gemm_mfma<<<dim3(40, 1, 1), 256, 0, stream>>>(
            h16, 3072, WpG, 2560, 16, 0, gadec, nullptr, 2560,
            bcat, 2560, 2, nullptr, 0);
    }

    // ---- all preds in one big GEMM ----
    preds_gemm<<<dim3(157, TT), 256, 0, stream>>>(hhist, WpF, b_fc, lens, out);
}

// Round 4
// 4372.525 us; speedup vs baseline: 2.7452x; 1.1512x over previous
//
#include <hip/hip_runtime.h>
#include <hip/hip_bf16.h>
#include <math.h>

#define BB 64
#define NPIX 196
#define ENCD 2048
#define DECD 512
#define VOCAB_N 10000
#define MAXLEN 52
#define TT 51
#define NPADFC 10048

// Output layout (floats): preds | captions | declens | alphas
#define PRED_SZ   (BB * TT * VOCAB_N)
#define CAPS_SZ   (BB * MAXLEN)
#define LENS_SZ   (BB)
#define ALPHAS_OFF (PRED_SZ + CAPS_SZ + LENS_SZ)

typedef __attribute__((ext_vector_type(8))) short short8;
typedef __attribute__((ext_vector_type(4))) short short4v;
typedef __attribute__((ext_vector_type(4))) float f32x4;

__device__ __forceinline__ float fsigm(float x) {
    return 1.0f / (1.0f + __expf(-x));
}
__device__ __forceinline__ float ftanh(float x) {
    x = fminf(fmaxf(x, -15.0f), 15.0f);
    float e = __expf(2.0f * x);
    return (e - 1.0f) / (e + 1.0f);
}
__device__ __forceinline__ float bf2f(unsigned short u) {
    union { unsigned int i; float f; } v;
    v.i = ((unsigned int)u) << 16;
    return v.f;
}
__device__ __forceinline__ unsigned short f2bf(float f) {
    union { float f; unsigned int i; } v;
    v.f = f;
    unsigned int r = v.i + 0x7FFFu + ((v.i >> 16) & 1u);
    return (unsigned short)(r >> 16);
}

// ---------------------------------------------------------------------------
// Generic MFMA GEMM (verified round-0/1 path). Used in-loop for the gates
// partials: gparts[kz] = xcat[:, kz-slice] @ WpL[kz]  (z=8, nkb=12).
// ---------------------------------------------------------------------------
__global__ __launch_bounds__(256) void gemm_mfma(
    const unsigned short* __restrict__ A, int lda,
    const unsigned short* __restrict__ Wp, int Npad,
    int nkb, long slice_stride,
    float* __restrict__ C, unsigned short* __restrict__ C16, long ldc,
    const float* __restrict__ bias, int N, int act,
    const int* __restrict__ caplen, int t)
{
    const int n0 = blockIdx.x * 64;
    const int m0 = blockIdx.y * 64;
    const int kz = blockIdx.z;
    A  += (size_t)kz * nkb * 32;
    Wp += (size_t)kz * nkb * Npad * 32;
    if (C) C += (size_t)kz * slice_stride;

    const int w  = threadIdx.x >> 6;
    const int l  = threadIdx.x & 63;
    const int lr = l & 15;
    const int q  = l >> 4;

    const unsigned short* ap = A + (size_t)(m0 + 16 * w + lr) * lda + q * 8;
    const unsigned short* bp = Wp + (size_t)(n0 + lr) * 32 + q * 8;
    const size_t bstep = (size_t)Npad * 32;

    f32x4 acc[4];
#pragma unroll
    for (int i = 0; i < 4; ++i) acc[i] = (f32x4){0.f, 0.f, 0.f, 0.f};

    short8 a  = *(const short8*)ap;
    short8 b0 = *(const short8*)(bp);
    short8 b1 = *(const short8*)(bp + 512);
    short8 b2 = *(const short8*)(bp + 1024);
    short8 b3 = *(const short8*)(bp + 1536);

    for (int kb = 0; kb < nkb; ++kb) {
        const size_t nxt = (kb + 1 < nkb) ? 1 : 0;
        const unsigned short* apn = ap + nxt * 32;
        const unsigned short* bpn = bp + nxt * bstep;
        short8 an  = *(const short8*)apn;
        short8 bn0 = *(const short8*)(bpn);
        short8 bn1 = *(const short8*)(bpn + 512);
        short8 bn2 = *(const short8*)(bpn + 1024);
        short8 bn3 = *(const short8*)(bpn + 1536);
        acc[0] = __builtin_amdgcn_mfma_f32_16x16x32_bf16(a, b0, acc[0], 0, 0, 0);
        acc[1] = __builtin_amdgcn_mfma_f32_16x16x32_bf16(a, b1, acc[1], 0, 0, 0);
        acc[2] = __builtin_amdgcn_mfma_f32_16x16x32_bf16(a, b2, acc[2], 0, 0, 0);
        acc[3] = __builtin_amdgcn_mfma_f32_16x16x32_bf16(a, b3, acc[3], 0, 0, 0);
        a = an; b0 = bn0; b1 = bn1; b2 = bn2; b3 = bn3;
        ap = apn; bp = bpn;
    }

    const int r0 = q * 4;
#pragma unroll
    for (int cf = 0; cf < 4; ++cf) {
        int col = n0 + cf * 16 + lr;
        if (col >= N) continue;
        float bv = bias ? bias[col] : 0.f;
#pragma unroll
        for (int r = 0; r < 4; ++r) {
            int row = m0 + 16 * w + r0 + r;
            float v = acc[cf][r] + bv;
            if (act == 1 || (act == 2 && col < 2048)) v = fsigm(v);
            if (caplen) v *= (t < caplen[row] - 1) ? 1.f : 0.f;
            if (C16) C16[(size_t)row * ldc + col] = f2bf(v);
            else     C [(size_t)row * ldc + col] = v;
        }
    }
}

// ---------------------------------------------------------------------------
// Mega step kernel. 64 blocks (one per batch row) x 512 threads.
//  1. (t>0) LSTM finish for step t-1: reduce 8 gparts slices, gate math,
//     masked c/h update, hhist[t-1] write. h row -> LDS (fp32).
//  2. gadec: [gate|adec] = h @ [W_fbeta|W_dec_att] via VALU dots, using
//     k-blocked packed WgK: WgK[(kk*2560+n)*8+u] = W[kk*8+u][n].
//  3. attention: e = tanh(attenc + adec)@Wf + bf, softmax -> alpha.
//  4. awe = sum_p alpha*enc16; xcat = [emb | gate*awe | h].
// ---------------------------------------------------------------------------
__global__ __launch_bounds__(512) void mega_step(
    const unsigned short* __restrict__ attenc16,
    const unsigned short* __restrict__ enc16,
    const unsigned short* __restrict__ WgK,
    const float* __restrict__ bfb, const float* __restrict__ bda,
    const float* __restrict__ Wf, const float* __restrict__ bf_,
    const float* __restrict__ emb, const int* __restrict__ caps,
    const int* __restrict__ caplen,
    const float* __restrict__ gparts, const float* __restrict__ bsum,
    int t,
    float* __restrict__ c, unsigned short* __restrict__ xcat,
    unsigned short* __restrict__ hhist,
    float* __restrict__ alphas_out)
{
    const int b = blockIdx.x;
    const int tid = threadIdx.x;
    const int lane = tid & 63, wid = tid >> 6;

    __shared__ float h_sh[512];
    __shared__ float av[512];
    __shared__ float wv[512];
    __shared__ float gate_s[2048];
    __shared__ float es[NPIX];
    __shared__ float alpha_s[NPIX];
    __shared__ float r8[8];
    __shared__ float smax, ssum;

    unsigned short* xr = xcat + (size_t)b * 3072;
    const int cl = caplen[b] - 1;

    // ---- 1. LSTM for step t-1 ----
    if (t > 0) {
        const int j = tid;
        const float* g = gparts + (size_t)b * 2048;
        float gi = bsum[j],        gf = bsum[512 + j];
        float gg = bsum[1024 + j], go = bsum[1536 + j];
#pragma unroll
        for (int s = 0; s < 8; ++s) {
            const float* pp = g + (size_t)s * BB * 2048;
            gi += pp[j]; gf += pp[512 + j]; gg += pp[1024 + j]; go += pp[1536 + j];
        }
        int cidx = b * 512 + j;
        float cn = fsigm(gf) * c[cidx] + fsigm(gi) * ftanh(gg);
        float hn = fsigm(go) * ftanh(cn);
        bool upd = ((t - 1) < cl);
        float hv;
        unsigned short hb;
        if (upd) {
            c[cidx] = cn;
            hb = f2bf(hn);
            xr[2560 + j] = hb;
            hv = hn;
        } else {
            hb = xr[2560 + j];
            hv = bf2f(hb);
        }
        hhist[((size_t)(t - 1) * BB + b) * 512 + j] = hb;
        h_sh[j] = hv;
    } else {
        h_sh[tid] = bf2f(xr[2560 + tid]);
    }
    wv[tid] = Wf[tid];
    __syncthreads();

    // ---- 2. gadec: thread computes cols tid+512*i, i=0..3 gate, i=4 adec ----
    float a5[5];
#pragma unroll
    for (int i = 0; i < 5; ++i) a5[i] = 0.f;
    for (int kk = 0; kk < 64; ++kk) {
        float h8[8];
#pragma unroll
        for (int u = 0; u < 8; ++u) h8[u] = h_sh[kk * 8 + u];
#pragma unroll
        for (int i = 0; i < 5; ++i) {
            short8 w8 = *(const short8*)(WgK + ((size_t)(kk * 2560 + tid + 512 * i)) * 8);
#pragma unroll
            for (int u = 0; u < 8; ++u)
                a5[i] += h8[u] * bf2f((unsigned short)w8[u]);
        }
    }
#pragma unroll
    for (int i = 0; i < 4; ++i)
        gate_s[tid + 512 * i] = fsigm(a5[i] + bfb[tid + 512 * i]);
    av[tid] = a5[4] + bda[tid];
    __syncthreads();

    // ---- 3. attention ----
    float mya[8], myw[8];
#pragma unroll
    for (int i = 0; i < 8; ++i) {
        mya[i] = av[lane * 8 + i];
        myw[i] = wv[lane * 8 + i];
    }

    float bf0 = bf_[0];
    for (int p = wid; p < NPIX; p += 8) {
        const unsigned short* ae = attenc16 + ((size_t)(b * NPIX + p)) * 512 + lane * 8;
        short8 e8 = *(const short8*)ae;
        float s = 0.f;
#pragma unroll
        for (int i = 0; i < 8; ++i)
            s += ftanh(bf2f((unsigned short)e8[i]) + mya[i]) * myw[i];
        for (int off = 32; off; off >>= 1) s += __shfl_down(s, off);
        if (lane == 0) es[p] = s + bf0;
    }
    __syncthreads();

    float v = (tid < NPIX) ? es[tid] : -1e30f;
    float m = v;
    for (int off = 32; off; off >>= 1) m = fmaxf(m, __shfl_down(m, off));
    if (lane == 0) r8[wid] = m;
    __syncthreads();
    if (tid == 0) {
        float mm = r8[0];
#pragma unroll
        for (int i = 1; i < 8; ++i) mm = fmaxf(mm, r8[i]);
        smax = mm;
    }
    __syncthreads();

    float ev = (tid < NPIX) ? __expf(v - smax) : 0.0f;
    float s = ev;
    for (int off = 32; off; off >>= 1) s += __shfl_down(s, off);
    if (lane == 0) r8[wid] = s;
    __syncthreads();
    if (tid == 0) {
        float ss = 0.f;
#pragma unroll
        for (int i = 0; i < 8; ++i) ss += r8[i];
        ssum = ss;
    }
    __syncthreads();

    float mk = (t < cl) ? 1.0f : 0.0f;
    if (tid < NPIX) {
        float a = ev / ssum;
        alpha_s[tid] = a;
        alphas_out[((size_t)b * TT + t) * NPIX + tid] = a * mk;
    }
    __syncthreads();

    // ---- 4. awe + xcat ----
    int d0 = tid * 4;
    const unsigned short* e = enc16 + (size_t)b * NPIX * ENCD + d0;
    float s0 = 0.f, s1 = 0.f, s2 = 0.f, s3 = 0.f;
    for (int p = 0; p < NPIX; ++p) {
        short4v v4 = *(const short4v*)(e + (size_t)p * ENCD);
        float a = alpha_s[p];
        s0 += a * bf2f((unsigned short)v4[0]);
        s1 += a * bf2f((unsigned short)v4[1]);
        s2 += a * bf2f((unsigned short)v4[2]);
        s3 += a * bf2f((unsigned short)v4[3]);
    }
    xr[512 + d0 + 0] = f2bf(s0 * gate_s[d0 + 0]);
    xr[512 + d0 + 1] = f2bf(s1 * gate_s[d0 + 1]);
    xr[512 + d0 + 2] = f2bf(s2 * gate_s[d0 + 2]);
    xr[512 + d0 + 3] = f2bf(s3 * gate_s[d0 + 3]);

    int wword = caps[b * MAXLEN + t];
    xr[tid] = f2bf(emb[(size_t)wword * 512 + tid]);
}

// ---------------------------------------------------------------------------
// Final LSTM (t = TT-1): reduce 8 slices, masked update, hhist[TT-1].
// ---------------------------------------------------------------------------
__global__ __launch_bounds__(256) void final_lstm(
    const float* __restrict__ gparts, const float* __restrict__ bsum,
    const int* __restrict__ caplen, int t,
    float* __restrict__ c, unsigned short* __restrict__ xcat,
    unsigned short* __restrict__ hhist)
{
    int idx = blockIdx.x * 256 + threadIdx.x;  // 0..32767
    int b = idx >> 9, j = idx & 511;
    const float* g = gparts + (size_t)b * 2048;
    float gi = bsum[j],        gf = bsum[512 + j];
    float gg = bsum[1024 + j], go = bsum[1536 + j];
#pragma unroll
    for (int s = 0; s < 8; ++s) {
        const float* p = g + (size_t)s * BB * 2048;
        gi += p[j]; gf += p[512 + j]; gg += p[1024 + j]; go += p[1536 + j];
    }
    float cn = fsigm(gf) * c[idx] + fsigm(gi) * ftanh(gg);
    float hn = fsigm(go) * ftanh(cn);
    unsigned short* hx = xcat + (size_t)b * 3072 + 2560 + j;
    unsigned short oldh = *hx;
    bool upd = (t < caplen[b] - 1);
    unsigned short hv = upd ? f2bf(hn) : oldh;
    if (upd) { c[idx] = cn; *hx = hv; }
    hhist[((size_t)t * BB + b) * 512 + j] = hv;
}

// ---------------------------------------------------------------------------
// Final preds GEMM over the whole h history: rows = t*64+b (3264), K=512.
// ---------------------------------------------------------------------------
__global__ __launch_bounds__(256) void preds_gemm(
    const unsigned short* __restrict__ hhist,
    const unsigned short* __restrict__ WpF,
    const float* __restrict__ bfc,
    const int* __restrict__ caplen,
    float* __restrict__ out)
{
    const int n0 = blockIdx.x * 64;
    const int row0 = blockIdx.y * 64;
    const int w  = threadIdx.x >> 6;
    const int l  = threadIdx.x & 63;
    const int lr = l & 15;
    const int q  = l >> 4;

    const unsigned short* ap = hhist + (size_t)(row0 + 16 * w + lr) * 512 + q * 8;
    const unsigned short* bp = WpF + (size_t)(n0 + lr) * 32 + q * 8;
    const size_t bstep = (size_t)NPADFC * 32;

    f32x4 acc[4];
#pragma unroll
    for (int i = 0; i < 4; ++i) acc[i] = (f32x4){0.f, 0.f, 0.f, 0.f};

    short8 a  = *(const short8*)ap;
    short8 b0 = *(const short8*)(bp);
    short8 b1 = *(const short8*)(bp + 512);
    short8 b2 = *(const short8*)(bp + 1024);
    short8 b3 = *(const short8*)(bp + 1536);

    for (int kb = 0; kb < 16; ++kb) {
        const size_t nxt = (kb + 1 < 16) ? 1 : 0;
        const unsigned short* apn = ap + nxt * 32;
        const unsigned short* bpn = bp + nxt * bstep;
        short8 an  = *(const short8*)apn;
        short8 bn0 = *(const short8*)(bpn);
        short8 bn1 = *(const short8*)(bpn + 512);
        short8 bn2 = *(const short8*)(bpn + 1024);
        short8 bn3 = *(const short8*)(bpn + 1536);
        acc[0] = __builtin_amdgcn_mfma_f32_16x16x32_bf16(a, b0, acc[0], 0, 0, 0);
        acc[1] = __builtin_amdgcn_mfma_f32_16x16x32_bf16(a, b1, acc[1], 0, 0, 0);
        acc[2] = __builtin_amdgcn_mfma_f32_16x16x32_bf16(a, b2, acc[2], 0, 0, 0);
        acc[3] = __builtin_amdgcn_mfma_f32_16x16x32_bf16(a, b3, acc[3], 0, 0, 0);
        a = an; b0 = bn0; b1 = bn1; b2 = bn2; b3 = bn3;
        ap = apn; bp = bpn;
    }

    const int r0 = q * 4;
#pragma unroll
    for (int cf = 0; cf < 4; ++cf) {
        int col = n0 + cf * 16 + lr;
        if (col >= VOCAB_N) continue;
        float bv = bfc[col];
#pragma unroll
        for (int r = 0; r < 4; ++r) {
            int row = row0 + 16 * w + r0 + r;
            int tt = row >> 6, b = row & 63;
            float mk = (tt < caplen[b] - 1) ? 1.f : 0.f;
            out[((size_t)b * TT + tt) * VOCAB_N + col] = (acc[cf][r] + bv) * mk;
        }
    }
}

// ---------------------------------------------------------------------------
// Weight packing: Wp[(kb*Npad + n)*32 + kk] = src[k=kb*32+kk][n], bf16.
// mode 0: single source W1 (K x N1), pad n>=N1 with 0
// mode 2: k-concat [W1 (K1 x N1) ; W2 ((K-K1) x N1)], Npad = N1
// ---------------------------------------------------------------------------
__global__ void pack_kernel(const float* __restrict__ W1, const float* __restrict__ W2,
                            int N1, int N2, int K1, int Npad, int mode,
                            unsigned short* __restrict__ Wp, int total)
{
    int idx = blockIdx.x * 256 + threadIdx.x;
    if (idx >= total) return;
    int kk = idx & 31;
    int r  = idx >> 5;
    int n  = r % Npad;
    int kb = r / Npad;
    int k  = kb * 32 + kk;
    float v = 0.f;
    if (mode == 0) {
        if (n < N1) v = W1[(size_t)k * N1 + n];
    } else if (mode == 1) {
        v = (n < N1) ? W1[(size_t)k * N1 + n] : W2[(size_t)k * N2 + (n - N1)];
    } else {
        v = (k < K1) ? W1[(size_t)k * N1 + n] : W2[(size_t)(k - K1) * N1 + n];
    }
    Wp[idx] = f2bf(v);
}

// k-blocked pack for the VALU gadec: WgK[(kk*2560+n)*8+u] = W[kk*8+u][n],
// W = [W_fbeta (512x2048) | W_dec_att (512x512)] n-concat, K=512.
__global__ void packGK_kernel(const float* __restrict__ Wfb,
                              const float* __restrict__ Wda,
                              unsigned short* __restrict__ Wp, int total)
{
    int idx = blockIdx.x * 256 + threadIdx.x;
    if (idx >= total) return;
    int u  = idx & 7;
    int r  = idx >> 3;
    int n  = r % 2560;
    int kk = r / 2560;
    int k  = kk * 8 + u;
    float v = (n < 2048) ? Wfb[(size_t)k * 2048 + n]
                         : Wda[(size_t)k * 512 + (n - 2048)];
    Wp[idx] = f2bf(v);
}

__global__ void cast_kernel(const float* __restrict__ src,
                            unsigned short* __restrict__ dst, int n)
{
    int i = (blockIdx.x * 256 + threadIdx.x) * 4;
    if (i >= n) return;
    float4 v = *(const float4*)(src + i);
    dst[i]     = f2bf(v.x);
    dst[i + 1] = f2bf(v.y);
    dst[i + 2] = f2bf(v.z);
    dst[i + 3] = f2bf(v.w);
}

__global__ void bsum_prep(const float* __restrict__ bih, const float* __restrict__ bhh,
                          float* __restrict__ bsum)
{
    int i = blockIdx.x * 256 + threadIdx.x;
    if (i < 2048) bsum[i] = bih[i] + bhh[i];
}

__global__ void mean_kernel(const float* __restrict__ enc, float* __restrict__ me)
{
    int d = blockIdx.x * 256 + threadIdx.x;
    int b = blockIdx.y;
    const float* p = enc + (size_t)b * NPIX * ENCD + d;
    float s = 0.0f;
    for (int q = 0; q < NPIX; ++q) s += p[(size_t)q * ENCD];
    me[b * ENCD + d] = s * (1.0f / 196.0f);
}

// h0 (bf16 into xcat h-region) + c0 (fp32)
__global__ void inithc_kernel(const float* __restrict__ me,
                              const float* __restrict__ Wh, const float* __restrict__ bh,
                              const float* __restrict__ Wc, const float* __restrict__ bc,
                              unsigned short* __restrict__ xcat, float* __restrict__ c)
{
    int idx = blockIdx.x * 256 + threadIdx.x;  // 0..32767
    int b = idx >> 9, j = idx & 511;
    const float* m = me + b * ENCD;
    float sh = bh[j], sc = bc[j];
    for (int k = 0; k < ENCD; ++k) {
        float mv = m[k];
        sh += mv * Wh[(size_t)k * DECD + j];
        sc += mv * Wc[(size_t)k * DECD + j];
    }
    xcat[(size_t)b * 3072 + 2560 + j] = f2bf(sh);
    c[idx] = sc;
}

__global__ void copy_misc(const int* __restrict__ caps, const int* __restrict__ lens,
                          float* __restrict__ out)
{
    int i = blockIdx.x * 256 + threadIdx.x;
    if (i < CAPS_SZ) out[PRED_SZ + i] = (float)caps[i];
    else if (i < CAPS_SZ + LENS_SZ) out[PRED_SZ + i] = (float)(lens[i - CAPS_SZ] - 1);
}

// ---------------------------------------------------------------------------
// Setup attenc GEMM: attenc16 = enc16 @ W_enc_att + b  (M=12544, N=512, K=2048)
// 128x128 tiles, grid (4, 98).
// ---------------------------------------------------------------------------
__global__ __launch_bounds__(256) void encatt_gemm(
    const unsigned short* __restrict__ A,
    const unsigned short* __restrict__ Wp,
    const float* __restrict__ bias,
    unsigned short* __restrict__ C16)
{
    const int n0 = blockIdx.x * 128;
    const int m0 = blockIdx.y * 128;
    const int w  = threadIdx.x >> 6;
    const int l  = threadIdx.x & 63;
    const int lr = l & 15;
    const int q  = l >> 4;

    const unsigned short* ap = A + (size_t)(m0 + 16 * w + lr) * 2048 + q * 8;
    const unsigned short* bp = Wp + (size_t)(n0 + lr) * 32 + q * 8;
    const size_t bstep = (size_t)512 * 32;

    f32x4 acc[16];
#pragma unroll
    for (int i = 0; i < 16; ++i) acc[i] = (f32x4){0.f, 0.f, 0.f, 0.f};

    short8 a0 = *(const short8*)(ap);
    short8 a1 = *(const short8*)(ap + 64 * 2048);
    short8 b[8];
#pragma unroll
    for (int nt = 0; nt < 8; ++nt) b[nt] = *(const short8*)(bp + nt * 512);

    for (int kb = 0; kb < 64; ++kb) {
        const size_t nxt = (kb + 1 < 64) ? 1 : 0;
        const unsigned short* apn = ap + nxt * 32;
        const unsigned short* bpn = bp + nxt * bstep;
        short8 an0 = *(const short8*)(apn);
        short8 an1 = *(const short8*)(apn + 64 * 2048);
        short8 bn[8];
#pragma unroll
        for (int nt = 0; nt < 8; ++nt) bn[nt] = *(const short8*)(bpn + nt * 512);
#pragma unroll
        for (int nt = 0; nt < 8; ++nt) {
            acc[nt]     = __builtin_amdgcn_mfma_f32_16x16x32_bf16(a0, b[nt], acc[nt], 0, 0, 0);
            acc[8 + nt] = __builtin_amdgcn_mfma_f32_16x16x32_bf16(a1, b[nt], acc[8 + nt], 0, 0, 0);
        }
        a0 = an0; a1 = an1;
#pragma unroll
        for (int nt = 0; nt < 8; ++nt) b[nt] = bn[nt];
        ap = apn; bp = bpn;
    }

    const int r0 = q * 4;
#pragma unroll
    for (int mt = 0; mt < 2; ++mt) {
#pragma unroll
        for (int nt = 0; nt < 8; ++nt) {
            int col = n0 + nt * 16 + lr;
            float bv = bias[col];
#pragma unroll
            for (int r = 0; r < 4; ++r) {
                int row = m0 + mt * 64 + 16 * w + r0 + r;
                C16[(size_t)row * 512 + col] = f2bf(acc[mt * 8 + nt][r] + bv);
            }
        }
    }
}

// ---------------------------------------------------------------------------
extern "C" void kernel_launch(void* const* d_in, const int* in_sizes, int n_in,
                              void* d_out, int out_size, void* d_ws, size_t ws_size,
                              hipStream_t stream)
{
    (void)in_sizes; (void)n_in; (void)out_size; (void)ws_size;
    const float* enc        = (const float*)d_in[0];
    const int*   caps       = (const int*)d_in[1];
    const int*   lens       = (const int*)d_in[2];
    const float* emb        = (const float*)d_in[3];
    const float* W_enc_att  = (const float*)d_in[4];
    const float* b_enc_att  = (const float*)d_in[5];
    const float* W_dec_att  = (const float*)d_in[6];
    const float* b_dec_att  = (const float*)d_in[7];
    const float* W_full_att = (const float*)d_in[8];
    const float* b_full_att = (const float*)d_in[9];
    const float* W_init_h   = (const float*)d_in[10];
    const float* b_init_h   = (const float*)d_in[11];
    const float* W_init_c   = (const float*)d_in[12];
    const float* b_init_c   = (const float*)d_in[13];
    const float* W_fbeta    = (const float*)d_in[14];
    const float* b_fbeta    = (const float*)d_in[15];
    const float* W_ih       = (const float*)d_in[16];
    const float* W_hh       = (const float*)d_in[17];
    const float* b_ih       = (const float*)d_in[18];
    const float* b_hh       = (const float*)d_in[19];
    const float* W_fc       = (const float*)d_in[20];
    const float* b_fc       = (const float*)d_in[21];
    float* out = (float*)d_out;

    // ---- workspace carve-up ----
    char* p = (char*)d_ws;
    unsigned short* enc16   = (unsigned short*)p; p += (size_t)BB * NPIX * ENCD * 2;   // 51.4MB
    unsigned short* attenc16= (unsigned short*)p; p += (size_t)BB * NPIX * 512 * 2;    // 12.8MB
    unsigned short* WpL     = (unsigned short*)p; p += (size_t)96 * 2048 * 32 * 2;     // 12.6MB gates K=3072 Npad=2048
    unsigned short* WpF     = (unsigned short*)p; p += (size_t)16 * NPADFC * 32 * 2;   // 10.3MB fc K=512
    unsigned short* WpE     = (unsigned short*)p; p += (size_t)64 * 512 * 32 * 2;      // 2.1MB  enc_att K=2048
    unsigned short* WgK     = (unsigned short*)p; p += (size_t)64 * 2560 * 8 * 2;      // 2.6MB  fbeta|dec_att k-blocked
    unsigned short* xcat    = (unsigned short*)p; p += (size_t)BB * 3072 * 2;          // 384KB
    unsigned short* hhist   = (unsigned short*)p; p += (size_t)TT * BB * 512 * 2;      // 3.3MB
    float* gparts = (float*)p; p += (size_t)8 * BB * 2048 * 4;                         // 4MB
    float* c      = (float*)p; p += (size_t)BB * 512 * 4;                              // 128KB
    float* me     = (float*)p; p += (size_t)BB * ENCD * 4;                             // 512KB
    float* bsum   = (float*)p; p += 2048 * 4;

    // ---- setup ----
    {
        int n = BB * NPIX * ENCD;
        cast_kernel<<<(n / 4 + 255) / 256, 256, 0, stream>>>(enc, enc16, n);
    }
    { int tot = 96 * 2048 * 32;
      pack_kernel<<<(tot + 255) / 256, 256, 0, stream>>>(W_ih, W_hh, 2048, 2048, 2560, 2048, 2, WpL, tot); }
    { int tot = 16 * NPADFC * 32;
      pack_kernel<<<(tot + 255) / 256, 256, 0, stream>>>(W_fc, nullptr, VOCAB_N, 0, 0, NPADFC, 0, WpF, tot); }
    { int tot = 64 * 512 * 32;
      pack_kernel<<<(tot + 255) / 256, 256, 0, stream>>>(W_enc_att, nullptr, 512, 0, 0, 512, 0, WpE, tot); }
    { int tot = 64 * 2560 * 8;
      packGK_kernel<<<(tot + 255) / 256, 256, 0, stream>>>(W_fbeta, W_dec_att, WgK, tot); }
    bsum_prep<<<8, 256, 0, stream>>>(b_ih, b_hh, bsum);
    mean_kernel<<<dim3(8, 64), 256, 0, stream>>>(enc, me);
    inithc_kernel<<<128, 256, 0, stream>>>(me, W_init_h, b_init_h, W_init_c, b_init_c, xcat, c);
    encatt_gemm<<<dim3(4, 98), 256, 0, stream>>>(enc16, WpE, b_enc_att, attenc16);
    copy_misc<<<14, 256, 0, stream>>>(caps, lens, out);

    // ---- decode loop: 2 kernels/step ----
    for (int t = 0; t < TT; ++t) {
        mega_step<<<64, 512, 0, stream>>>(
            attenc16, enc16, WgK, b_fbeta, b_dec_att,
            W_full_att, b_full_att, emb, caps, lens,
            gparts, bsum, t, c, xcat, hhist, out + ALPHAS_OFF);
        gemm_mfma<<<dim3(32, 1, 8), 256, 0, stream>>>(
            xcat, 3072, WpL, 2048, 12, (long)BB * 2048, gparts, nullptr, 2048,
            nullptr, 2048, 0, nullptr, 0);
    }

    // final LSTM for t = TT-1, then all preds in one big GEMM
    final_lstm<<<128, 256, 0, stream>>>(gparts, bsum, lens, TT - 1, c, xcat, hhist);
    preds_gemm<<<dim3(157, TT), 256, 0, stream>>>(hhist, WpF, b_fc, lens, out);
}

// Round 5
// 3586.263 us; speedup vs baseline: 3.3471x; 1.2192x over previous
//
#include <hip/hip_runtime.h>
#include <hip/hip_bf16.h>
#include <math.h>

#define BB 64
#define NPIX 196
#define ENCD 2048
#define DECD 512
#define VOCAB_N 10000
#define MAXLEN 52
#define TT 51
#define NPADFC 10048

// Output layout (floats): preds | captions | declens | alphas
#define PRED_SZ   (BB * TT * VOCAB_N)
#define CAPS_SZ   (BB * MAXLEN)
#define LENS_SZ   (BB)
#define ALPHAS_OFF (PRED_SZ + CAPS_SZ + LENS_SZ)

typedef __attribute__((ext_vector_type(8))) short short8;
typedef __attribute__((ext_vector_type(4))) short short4v;
typedef __attribute__((ext_vector_type(4))) float f32x4;

__device__ __forceinline__ float fsigm(float x) {
    return 1.0f / (1.0f + __expf(-x));
}
__device__ __forceinline__ float ftanh(float x) {
    x = fminf(fmaxf(x, -15.0f), 15.0f);
    float e = __expf(2.0f * x);
    return (e - 1.0f) / (e + 1.0f);
}
__device__ __forceinline__ float bf2f(unsigned short u) {
    union { unsigned int i; float f; } v;
    v.i = ((unsigned int)u) << 16;
    return v.f;
}
__device__ __forceinline__ unsigned short f2bf(float f) {
    union { float f; unsigned int i; } v;
    v.f = f;
    unsigned int r = v.i + 0x7FFFu + ((v.i >> 16) & 1u);
    return (unsigned short)(r >> 16);
}

// ---------------------------------------------------------------------------
// Generic MFMA GEMM (verified round-0/1 path). Used for the in-loop gadec:
// gadec = [sigmoid(h@Wfbeta+b) | h@Wd+bd], 40 blocks, A = hh[t] (lda 512).
// ---------------------------------------------------------------------------
__global__ __launch_bounds__(256) void gemm_mfma(
    const unsigned short* __restrict__ A, int lda,
    const unsigned short* __restrict__ Wp, int Npad,
    int nkb, long slice_stride,
    float* __restrict__ C, unsigned short* __restrict__ C16, long ldc,
    const float* __restrict__ bias, int N, int act,
    const int* __restrict__ caplen, int t)
{
    const int n0 = blockIdx.x * 64;
    const int m0 = blockIdx.y * 64;
    const int kz = blockIdx.z;
    A  += (size_t)kz * nkb * 32;
    Wp += (size_t)kz * nkb * Npad * 32;
    if (C) C += (size_t)kz * slice_stride;

    const int w  = threadIdx.x >> 6;
    const int l  = threadIdx.x & 63;
    const int lr = l & 15;
    const int q  = l >> 4;

    const unsigned short* ap = A + (size_t)(m0 + 16 * w + lr) * lda + q * 8;
    const unsigned short* bp = Wp + (size_t)(n0 + lr) * 32 + q * 8;
    const size_t bstep = (size_t)Npad * 32;

    f32x4 acc[4];
#pragma unroll
    for (int i = 0; i < 4; ++i) acc[i] = (f32x4){0.f, 0.f, 0.f, 0.f};

    short8 a  = *(const short8*)ap;
    short8 b0 = *(const short8*)(bp);
    short8 b1 = *(const short8*)(bp + 512);
    short8 b2 = *(const short8*)(bp + 1024);
    short8 b3 = *(const short8*)(bp + 1536);

    for (int kb = 0; kb < nkb; ++kb) {
        const size_t nxt = (kb + 1 < nkb) ? 1 : 0;
        const unsigned short* apn = ap + nxt * 32;
        const unsigned short* bpn = bp + nxt * bstep;
        short8 an  = *(const short8*)apn;
        short8 bn0 = *(const short8*)(bpn);
        short8 bn1 = *(const short8*)(bpn + 512);
        short8 bn2 = *(const short8*)(bpn + 1024);
        short8 bn3 = *(const short8*)(bpn + 1536);
        acc[0] = __builtin_amdgcn_mfma_f32_16x16x32_bf16(a, b0, acc[0], 0, 0, 0);
        acc[1] = __builtin_amdgcn_mfma_f32_16x16x32_bf16(a, b1, acc[1], 0, 0, 0);
        acc[2] = __builtin_amdgcn_mfma_f32_16x16x32_bf16(a, b2, acc[2], 0, 0, 0);
        acc[3] = __builtin_amdgcn_mfma_f32_16x16x32_bf16(a, b3, acc[3], 0, 0, 0);
        a = an; b0 = bn0; b1 = bn1; b2 = bn2; b3 = bn3;
        ap = apn; bp = bpn;
    }

    const int r0 = q * 4;
#pragma unroll
    for (int cf = 0; cf < 4; ++cf) {
        int col = n0 + cf * 16 + lr;
        if (col >= N) continue;
        float bv = bias ? bias[col] : 0.f;
#pragma unroll
        for (int r = 0; r < 4; ++r) {
            int row = m0 + 16 * w + r0 + r;
            float v = acc[cf][r] + bv;
            if (act == 1 || (act == 2 && col < 2048)) v = fsigm(v);
            if (caplen) v *= (t < caplen[row] - 1) ? 1.f : 0.f;
            if (C16) C16[(size_t)row * ldc + col] = f2bf(v);
            else     C [(size_t)row * ldc + col] = v;
        }
    }
}

// ---------------------------------------------------------------------------
// Fused gates GEMM + LSTM. 128 blocks (4 m-tiles x 32 n-tiles) x 256 thr.
// WpLi gate-interleaved: packed col n = unit (n>>2), gate (n&3).
// Each block: 16 rows x 64 packed cols (= 16 units, all 4 gates); K=3072
// split over the 4 waves (24 kb each), LDS-reduced; LSTM epilogue updates
// c and writes hnext (ping-pong with hprev -> race-free).
// A operand: cols [0,2560) from xcatEG, [2560,3072) from hprev.
// ---------------------------------------------------------------------------
__global__ __launch_bounds__(256) void gateslstm_kernel(
    const unsigned short* __restrict__ xcatEG,   // [64][2560] emb|gate*awe
    const unsigned short* __restrict__ hprev,    // [64][512]
    const unsigned short* __restrict__ WpLi,
    const float* __restrict__ bsum,
    const int* __restrict__ caplen, int t,
    float* __restrict__ c,
    unsigned short* __restrict__ hnext)          // [64][512]
{
    __shared__ float gt[4][16][68];

    const int bx = blockIdx.x;
    const int nx = bx & 31;
    const int my = bx >> 5;
    const int m0 = my * 16;
    const int n0 = nx * 64;
    const int tid = threadIdx.x;
    const int ws = tid >> 6;       // wave = K-slice (768 each)
    const int l  = tid & 63;
    const int lr = l & 15;
    const int q  = l >> 4;

    const unsigned short* arow_x = xcatEG + (size_t)(m0 + lr) * 2560;
    const unsigned short* arow_h = hprev  + (size_t)(m0 + lr) * 512;
    const int kbase = ws * 768 + q * 8;

    const unsigned short* bp = WpLi + ((size_t)(ws * 24) * 2048 + n0 + lr) * 32 + q * 8;
    const size_t bstep = (size_t)2048 * 32;

    f32x4 acc[4];
#pragma unroll
    for (int i = 0; i < 4; ++i) acc[i] = (f32x4){0.f, 0.f, 0.f, 0.f};

#define ALOAD(kb) ({ int k0_ = kbase + (kb) * 32; \
    (k0_ < 2560) ? *(const short8*)(arow_x + k0_) \
                 : *(const short8*)(arow_h + (k0_ - 2560)); })

    short8 a  = ALOAD(0);
    short8 b0 = *(const short8*)(bp);
    short8 b1 = *(const short8*)(bp + 512);
    short8 b2 = *(const short8*)(bp + 1024);
    short8 b3 = *(const short8*)(bp + 1536);

    for (int kb = 0; kb < 24; ++kb) {
        const int kn = (kb + 1 < 24) ? kb + 1 : kb;
        const unsigned short* bpn = bp + ((kb + 1 < 24) ? bstep : 0);
        short8 an  = ALOAD(kn);
        short8 bn0 = *(const short8*)(bpn);
        short8 bn1 = *(const short8*)(bpn + 512);
        short8 bn2 = *(const short8*)(bpn + 1024);
        short8 bn3 = *(const short8*)(bpn + 1536);
        acc[0] = __builtin_amdgcn_mfma_f32_16x16x32_bf16(a, b0, acc[0], 0, 0, 0);
        acc[1] = __builtin_amdgcn_mfma_f32_16x16x32_bf16(a, b1, acc[1], 0, 0, 0);
        acc[2] = __builtin_amdgcn_mfma_f32_16x16x32_bf16(a, b2, acc[2], 0, 0, 0);
        acc[3] = __builtin_amdgcn_mfma_f32_16x16x32_bf16(a, b3, acc[3], 0, 0, 0);
        a = an; b0 = bn0; b1 = bn1; b2 = bn2; b3 = bn3;
        bp = bpn;
    }
#undef ALOAD

    const int r0 = q * 4;
#pragma unroll
    for (int cf = 0; cf < 4; ++cf)
#pragma unroll
        for (int r = 0; r < 4; ++r)
            gt[ws][r0 + r][cf * 16 + lr] = acc[cf][r];
    __syncthreads();

    // LSTM epilogue: 256 threads -> (row, unit) pairs, 16x16
    const int row = tid & 15;
    const int jj  = tid >> 4;
    const int b   = m0 + row;
    const int j   = nx * 16 + jj;
    const int lc  = 4 * jj;
    float gi = bsum[j],        gf = bsum[512 + j];
    float gg = bsum[1024 + j], go = bsum[1536 + j];
#pragma unroll
    for (int s = 0; s < 4; ++s) {
        gi += gt[s][row][lc + 0];
        gf += gt[s][row][lc + 1];
        gg += gt[s][row][lc + 2];
        go += gt[s][row][lc + 3];
    }
    const int cidx = b * 512 + j;
    float cn = fsigm(gf) * c[cidx] + fsigm(gi) * ftanh(gg);
    float hn = fsigm(go) * ftanh(cn);
    bool upd = (t < caplen[b] - 1);
    if (upd) c[cidx] = cn;
    hnext[cidx] = upd ? f2bf(hn) : hprev[cidx];
}

// ---------------------------------------------------------------------------
// Attention + awe + xcat build (round-1 verified, h handling removed).
// One 512-thread block per batch row.
// ---------------------------------------------------------------------------
__global__ __launch_bounds__(512) void attawe_kernel(
    const float* __restrict__ gadec,
    const unsigned short* __restrict__ attenc16,
    const unsigned short* __restrict__ enc16,
    const float* __restrict__ Wf, const float* __restrict__ bf_,
    const float* __restrict__ emb, const int* __restrict__ caps,
    const int* __restrict__ caplen, int t,
    unsigned short* __restrict__ xcatEG,
    float* __restrict__ alphas_out)
{
    int b = blockIdx.x;
    int tid = threadIdx.x;
    int lane = tid & 63, wid = tid >> 6;
    __shared__ float av[512];
    __shared__ float wv[512];
    __shared__ float es[NPIX];
    __shared__ float alpha_s[NPIX];
    __shared__ float r8[8];
    __shared__ float smax, ssum;

    av[tid] = gadec[(size_t)b * 2560 + 2048 + tid];
    wv[tid] = Wf[tid];
    __syncthreads();

    float mya[8], myw[8];
#pragma unroll
    for (int i = 0; i < 8; ++i) {
        mya[i] = av[lane * 8 + i];
        myw[i] = wv[lane * 8 + i];
    }

    float bf0 = bf_[0];
    for (int p = wid; p < NPIX; p += 8) {
        const unsigned short* ae = attenc16 + ((size_t)(b * NPIX + p)) * 512 + lane * 8;
        short8 e8 = *(const short8*)ae;
        float s = 0.f;
#pragma unroll
        for (int i = 0; i < 8; ++i)
            s += ftanh(bf2f((unsigned short)e8[i]) + mya[i]) * myw[i];
        for (int off = 32; off; off >>= 1) s += __shfl_down(s, off);
        if (lane == 0) es[p] = s + bf0;
    }
    __syncthreads();

    float v = (tid < NPIX) ? es[tid] : -1e30f;
    float m = v;
    for (int off = 32; off; off >>= 1) m = fmaxf(m, __shfl_down(m, off));
    if (lane == 0) r8[wid] = m;
    __syncthreads();
    if (tid == 0) {
        float mm = r8[0];
#pragma unroll
        for (int i = 1; i < 8; ++i) mm = fmaxf(mm, r8[i]);
        smax = mm;
    }
    __syncthreads();

    float ev = (tid < NPIX) ? __expf(v - smax) : 0.0f;
    float s = ev;
    for (int off = 32; off; off >>= 1) s += __shfl_down(s, off);
    if (lane == 0) r8[wid] = s;
    __syncthreads();
    if (tid == 0) {
        float ss = 0.f;
#pragma unroll
        for (int i = 0; i < 8; ++i) ss += r8[i];
        ssum = ss;
    }
    __syncthreads();

    float mk = (t < caplen[b] - 1) ? 1.0f : 0.0f;
    if (tid < NPIX) {
        float a = ev / ssum;
        alpha_s[tid] = a;
        alphas_out[((size_t)b * TT + t) * NPIX + tid] = a * mk;
    }
    __syncthreads();

    // awe: 4 d's per thread (512*4 = 2048)
    int d0 = tid * 4;
    const unsigned short* e = enc16 + (size_t)b * NPIX * ENCD + d0;
    float s0 = 0.f, s1 = 0.f, s2 = 0.f, s3 = 0.f;
    for (int p = 0; p < NPIX; ++p) {
        short4v v4 = *(const short4v*)(e + (size_t)p * ENCD);
        float a = alpha_s[p];
        s0 += a * bf2f((unsigned short)v4[0]);
        s1 += a * bf2f((unsigned short)v4[1]);
        s2 += a * bf2f((unsigned short)v4[2]);
        s3 += a * bf2f((unsigned short)v4[3]);
    }
    unsigned short* xr = xcatEG + (size_t)b * 2560;
    const float* gtt = gadec + (size_t)b * 2560 + d0;
    xr[512 + d0 + 0] = f2bf(s0 * gtt[0]);
    xr[512 + d0 + 1] = f2bf(s1 * gtt[1]);
    xr[512 + d0 + 2] = f2bf(s2 * gtt[2]);
    xr[512 + d0 + 3] = f2bf(s3 * gtt[3]);

    int wword = caps[b * MAXLEN + t];
    xr[tid] = f2bf(emb[(size_t)wword * 512 + tid]);
}

// ---------------------------------------------------------------------------
// Final preds GEMM over h history hh[1..TT]: rows = t*64+b (3264), K=512.
// ---------------------------------------------------------------------------
__global__ __launch_bounds__(256) void preds_gemm(
    const unsigned short* __restrict__ hhist,   // = hh + 64*512
    const unsigned short* __restrict__ WpF,
    const float* __restrict__ bfc,
    const int* __restrict__ caplen,
    float* __restrict__ out)
{
    const int n0 = blockIdx.x * 64;
    const int row0 = blockIdx.y * 64;
    const int w  = threadIdx.x >> 6;
    const int l  = threadIdx.x & 63;
    const int lr = l & 15;
    const int q  = l >> 4;

    const unsigned short* ap = hhist + (size_t)(row0 + 16 * w + lr) * 512 + q * 8;
    const unsigned short* bp = WpF + (size_t)(n0 + lr) * 32 + q * 8;
    const size_t bstep = (size_t)NPADFC * 32;

    f32x4 acc[4];
#pragma unroll
    for (int i = 0; i < 4; ++i) acc[i] = (f32x4){0.f, 0.f, 0.f, 0.f};

    short8 a  = *(const short8*)ap;
    short8 b0 = *(const short8*)(bp);
    short8 b1 = *(const short8*)(bp + 512);
    short8 b2 = *(const short8*)(bp + 1024);
    short8 b3 = *(const short8*)(bp + 1536);

    for (int kb = 0; kb < 16; ++kb) {
        const size_t nxt = (kb + 1 < 16) ? 1 : 0;
        const unsigned short* apn = ap + nxt * 32;
        const unsigned short* bpn = bp + nxt * bstep;
        short8 an  = *(const short8*)apn;
        short8 bn0 = *(const short8*)(bpn);
        short8 bn1 = *(const short8*)(bpn + 512);
        short8 bn2 = *(const short8*)(bpn + 1024);
        short8 bn3 = *(const short8*)(bpn + 1536);
        acc[0] = __builtin_amdgcn_mfma_f32_16x16x32_bf16(a, b0, acc[0], 0, 0, 0);
        acc[1] = __builtin_amdgcn_mfma_f32_16x16x32_bf16(a, b1, acc[1], 0, 0, 0);
        acc[2] = __builtin_amdgcn_mfma_f32_16x16x32_bf16(a, b2, acc[2], 0, 0, 0);
        acc[3] = __builtin_amdgcn_mfma_f32_16x16x32_bf16(a, b3, acc[3], 0, 0, 0);
        a = an; b0 = bn0; b1 = bn1; b2 = bn2; b3 = bn3;
        ap = apn; bp = bpn;
    }

    const int r0 = q * 4;
#pragma unroll
    for (int cf = 0; cf < 4; ++cf) {
        int col = n0 + cf * 16 + lr;
        if (col >= VOCAB_N) continue;
        float bv = bfc[col];
#pragma unroll
        for (int r = 0; r < 4; ++r) {
            int row = row0 + 16 * w + r0 + r;
            int tt = row >> 6, b = row & 63;
            float mk = (tt < caplen[b] - 1) ? 1.f : 0.f;
            out[((size_t)b * TT + tt) * VOCAB_N + col] = (acc[cf][r] + bv) * mk;
        }
    }
}

// ---------------------------------------------------------------------------
// Weight packing: Wp[(kb*Npad + n)*32 + kk] = src[k=kb*32+kk][n], bf16.
// mode 0: single source; mode 1: n-concat [W1|W2].
// ---------------------------------------------------------------------------
__global__ void pack_kernel(const float* __restrict__ W1, const float* __restrict__ W2,
                            int N1, int N2, int K1, int Npad, int mode,
                            unsigned short* __restrict__ Wp, int total)
{
    int idx = blockIdx.x * 256 + threadIdx.x;
    if (idx >= total) return;
    int kk = idx & 31;
    int r  = idx >> 5;
    int n  = r % Npad;
    int kb = r / Npad;
    int k  = kb * 32 + kk;
    float v = 0.f;
    if (mode == 0) {
        if (n < N1) v = W1[(size_t)k * N1 + n];
    } else if (mode == 1) {
        v = (n < N1) ? W1[(size_t)k * N1 + n] : W2[(size_t)k * N2 + (n - N1)];
    } else {
        v = (k < K1) ? W1[(size_t)k * N1 + n] : W2[(size_t)(k - K1) * N1 + n];
    }
    Wp[idx] = f2bf(v);
}

// gate-interleaved pack of [W_ih(2560x2048); W_hh(512x2048)]:
// packed col n -> original col (n&3)*512 + (n>>2)   (verified round 3)
__global__ void packGi_kernel(const float* __restrict__ Wih,
                              const float* __restrict__ Whh,
                              unsigned short* __restrict__ Wp, int total)
{
    int idx = blockIdx.x * 256 + threadIdx.x;
    if (idx >= total) return;
    int kk = idx & 31;
    int r  = idx >> 5;
    int n  = r % 2048;
    int kb = r / 2048;
    int k  = kb * 32 + kk;
    int oc = (n & 3) * 512 + (n >> 2);
    float v = (k < 2560) ? Wih[(size_t)k * 2048 + oc]
                         : Whh[(size_t)(k - 2560) * 2048 + oc];
    Wp[idx] = f2bf(v);
}

__global__ void cast_kernel(const float* __restrict__ src,
                            unsigned short* __restrict__ dst, int n)
{
    int i = (blockIdx.x * 256 + threadIdx.x) * 4;
    if (i >= n) return;
    float4 v = *(const float4*)(src + i);
    dst[i]     = f2bf(v.x);
    dst[i + 1] = f2bf(v.y);
    dst[i + 2] = f2bf(v.z);
    dst[i + 3] = f2bf(v.w);
}

// bcat[2560] = [b_fbeta | b_dec_att]; bsum[2048] = b_ih + b_hh
__global__ void bias_prep(const float* __restrict__ bfb, const float* __restrict__ bda,
                          const float* __restrict__ bih, const float* __restrict__ bhh,
                          float* __restrict__ bcat, float* __restrict__ bsum)
{
    int i = blockIdx.x * 256 + threadIdx.x;
    if (i < 2048) { bcat[i] = bfb[i]; bsum[i] = bih[i] + bhh[i]; }
    else if (i < 2560) bcat[i] = bda[i - 2048];
}

__global__ void mean_kernel(const float* __restrict__ enc, float* __restrict__ me)
{
    int d = blockIdx.x * 256 + threadIdx.x;
    int b = blockIdx.y;
    const float* p = enc + (size_t)b * NPIX * ENCD + d;
    float s = 0.0f;
    for (int q = 0; q < NPIX; ++q) s += p[(size_t)q * ENCD];
    me[b * ENCD + d] = s * (1.0f / 196.0f);
}

// h0 (bf16 into hh[0]) + c0 (fp32)
__global__ void inithc_kernel(const float* __restrict__ me,
                              const float* __restrict__ Wh, const float* __restrict__ bh,
                              const float* __restrict__ Wc, const float* __restrict__ bc,
                              unsigned short* __restrict__ hh0, float* __restrict__ c)
{
    int idx = blockIdx.x * 256 + threadIdx.x;  // 0..32767
    int b = idx >> 9, j = idx & 511;
    const float* m = me + b * ENCD;
    float sh = bh[j], sc = bc[j];
    for (int k = 0; k < ENCD; ++k) {
        float mv = m[k];
        sh += mv * Wh[(size_t)k * DECD + j];
        sc += mv * Wc[(size_t)k * DECD + j];
    }
    hh0[idx] = f2bf(sh);
    c[idx] = sc;
}

__global__ void copy_misc(const int* __restrict__ caps, const int* __restrict__ lens,
                          float* __restrict__ out)
{
    int i = blockIdx.x * 256 + threadIdx.x;
    if (i < CAPS_SZ) out[PRED_SZ + i] = (float)caps[i];
    else if (i < CAPS_SZ + LENS_SZ) out[PRED_SZ + i] = (float)(lens[i - CAPS_SZ] - 1);
}

// ---------------------------------------------------------------------------
// Setup attenc GEMM: attenc16 = enc16 @ W_enc_att + b  (M=12544, N=512, K=2048)
// 128x128 tiles, grid (4, 98).
// ---------------------------------------------------------------------------
__global__ __launch_bounds__(256) void encatt_gemm(
    const unsigned short* __restrict__ A,
    const unsigned short* __restrict__ Wp,
    const float* __restrict__ bias,
    unsigned short* __restrict__ C16)
{
    const int n0 = blockIdx.x * 128;
    const int m0 = blockIdx.y * 128;
    const int w  = threadIdx.x >> 6;
    const int l  = threadIdx.x & 63;
    const int lr = l & 15;
    const int q  = l >> 4;

    const unsigned short* ap = A + (size_t)(m0 + 16 * w + lr) * 2048 + q * 8;
    const unsigned short* bp = Wp + (size_t)(n0 + lr) * 32 + q * 8;
    const size_t bstep = (size_t)512 * 32;

    f32x4 acc[16];
#pragma unroll
    for (int i = 0; i < 16; ++i) acc[i] = (f32x4){0.f, 0.f, 0.f, 0.f};

    short8 a0 = *(const short8*)(ap);
    short8 a1 = *(const short8*)(ap + 64 * 2048);
    short8 b[8];
#pragma unroll
    for (int nt = 0; nt < 8; ++nt) b[nt] = *(const short8*)(bp + nt * 512);

    for (int kb = 0; kb < 64; ++kb) {
        const size_t nxt = (kb + 1 < 64) ? 1 : 0;
        const unsigned short* apn = ap + nxt * 32;
        const unsigned short* bpn = bp + nxt * bstep;
        short8 an0 = *(const short8*)(apn);
        short8 an1 = *(const short8*)(apn + 64 * 2048);
        short8 bn[8];
#pragma unroll
        for (int nt = 0; nt < 8; ++nt) bn[nt] = *(const short8*)(bpn + nt * 512);
#pragma unroll
        for (int nt = 0; nt < 8; ++nt) {
            acc[nt]     = __builtin_amdgcn_mfma_f32_16x16x32_bf16(a0, b[nt], acc[nt], 0, 0, 0);
            acc[8 + nt] = __builtin_amdgcn_mfma_f32_16x16x32_bf16(a1, b[nt], acc[8 + nt], 0, 0, 0);
        }
        a0 = an0; a1 = an1;
#pragma unroll
        for (int nt = 0; nt < 8; ++nt) b[nt] = bn[nt];
        ap = apn; bp = bpn;
    }

    const int r0 = q * 4;
#pragma unroll
    for (int mt = 0; mt < 2; ++mt) {
#pragma unroll
        for (int nt = 0; nt < 8; ++nt) {
            int col = n0 + nt * 16 + lr;
            float bv = bias[col];
#pragma unroll
            for (int r = 0; r < 4; ++r) {
                int row = m0 + mt * 64 + 16 * w + r0 + r;
                C16[(size_t)row * 512 + col] = f2bf(acc[mt * 8 + nt][r] + bv);
            }
        }
    }
}

// ---------------------------------------------------------------------------
extern "C" void kernel_launch(void* const* d_in, const int* in_sizes, int n_in,
                              void* d_out, int out_size, void* d_ws, size_t ws_size,
                              hipStream_t stream)
{
    (void)in_sizes; (void)n_in; (void)out_size; (void)ws_size;
    const float* enc        = (const float*)d_in[0];
    const int*   caps       = (const int*)d_in[1];
    const int*   lens       = (const int*)d_in[2];
    const float* emb        = (const float*)d_in[3];
    const float* W_enc_att  = (const float*)d_in[4];
    const float* b_enc_att  = (const float*)d_in[5];
    const float* W_dec_att  = (const float*)d_in[6];
    const float* b_dec_att  = (const float*)d_in[7];
    const float* W_full_att = (const float*)d_in[8];
    const float* b_full_att = (const float*)d_in[9];
    const float* W_init_h   = (const float*)d_in[10];
    const float* b_init_h   = (const float*)d_in[11];
    const float* W_init_c   = (const float*)d_in[12];
    const float* b_init_c   = (const float*)d_in[13];
    const float* W_fbeta    = (const float*)d_in[14];
    const float* b_fbeta    = (const float*)d_in[15];
    const float* W_ih       = (const float*)d_in[16];
    const float* W_hh       = (const float*)d_in[17];
    const float* b_ih       = (const float*)d_in[18];
    const float* b_hh       = (const float*)d_in[19];
    const float* W_fc       = (const float*)d_in[20];
    const float* b_fc       = (const float*)d_in[21];
    float* out = (float*)d_out;

    // ---- workspace carve-up ----
    char* p = (char*)d_ws;
    unsigned short* enc16   = (unsigned short*)p; p += (size_t)BB * NPIX * ENCD * 2;   // 51.4MB
    unsigned short* attenc16= (unsigned short*)p; p += (size_t)BB * NPIX * 512 * 2;    // 12.8MB
    unsigned short* WpLi    = (unsigned short*)p; p += (size_t)96 * 2048 * 32 * 2;     // 12.6MB gates (interleaved) K=3072
    unsigned short* WpG     = (unsigned short*)p; p += (size_t)16 * 2560 * 32 * 2;     // 2.6MB  fbeta|dec_att K=512
    unsigned short* WpF     = (unsigned short*)p; p += (size_t)16 * NPADFC * 32 * 2;   // 10.3MB fc K=512
    unsigned short* WpE     = (unsigned short*)p; p += (size_t)64 * 512 * 32 * 2;      // 2.1MB  enc_att K=2048
    unsigned short* xcatEG  = (unsigned short*)p; p += (size_t)BB * 2560 * 2;          // 320KB
    unsigned short* hh      = (unsigned short*)p; p += (size_t)(TT + 1) * BB * 512 * 2;// 3.4MB  h(0)..h(TT)
    float* gadec  = (float*)p; p += (size_t)BB * 2560 * 4;                             // 640KB
    float* c      = (float*)p; p += (size_t)BB * 512 * 4;                              // 128KB
    float* me     = (float*)p; p += (size_t)BB * ENCD * 4;                             // 512KB
    float* bcat   = (float*)p; p += 2560 * 4;
    float* bsum   = (float*)p; p += 2048 * 4;

    // ---- setup ----
    {
        int n = BB * NPIX * ENCD;
        cast_kernel<<<(n / 4 + 255) / 256, 256, 0, stream>>>(enc, enc16, n);
    }
    { int tot = 96 * 2048 * 32;
      packGi_kernel<<<(tot + 255) / 256, 256, 0, stream>>>(W_ih, W_hh, WpLi, tot); }
    { int tot = 16 * 2560 * 32;
      pack_kernel<<<(tot + 255) / 256, 256, 0, stream>>>(W_fbeta, W_dec_att, 2048, 512, 0, 2560, 1, WpG, tot); }
    { int tot = 16 * NPADFC * 32;
      pack_kernel<<<(tot + 255) / 256, 256, 0, stream>>>(W_fc, nullptr, VOCAB_N, 0, 0, NPADFC, 0, WpF, tot); }
    { int tot = 64 * 512 * 32;
      pack_kernel<<<(tot + 255) / 256, 256, 0, stream>>>(W_enc_att, nullptr, 512, 0, 0, 512, 0, WpE, tot); }
    bias_prep<<<10, 256, 0, stream>>>(b_fbeta, b_dec_att, b_ih, b_hh, bcat, bsum);
    mean_kernel<<<dim3(8, 64), 256, 0, stream>>>(enc, me);
    inithc_kernel<<<128, 256, 0, stream>>>(me, W_init_h, b_init_h, W_init_c, b_init_c, hh, c);
    encatt_gemm<<<dim3(4, 98), 256, 0, stream>>>(enc16, WpE, b_enc_att, attenc16);
    copy_misc<<<14, 256, 0, stream>>>(caps, lens, out);

    // gadec(0) = [sigmoid(h0@Wfbeta+b) | h0@Wd+bd]
    gemm_mfma<<<dim3(40, 1, 1), 256, 0, stream>>>(
        hh, 512, WpG, 2560, 16, 0, gadec, nullptr, 2560,
        bcat, 2560, 2, nullptr, 0);

    // ---- decode loop: 3 kernels/step (2 on the last) ----
    for (int t = 0; t < TT; ++t) {
        attawe_kernel<<<64, 512, 0, stream>>>(
            gadec, attenc16, enc16, W_full_att, b_full_att,
            emb, caps, lens, t, xcatEG, out + ALPHAS_OFF);
        gateslstm_kernel<<<128, 256, 0, stream>>>(
            xcatEG, hh + (size_t)t * BB * 512, WpLi, bsum, lens, t,
            c, hh + (size_t)(t + 1) * BB * 512);
        if (t + 1 < TT) {
            gemm_mfma<<<dim3(40, 1, 1), 256, 0, stream>>>(
                hh + (size_t)(t + 1) * BB * 512, 512, WpG, 2560, 16, 0,
                gadec, nullptr, 2560, bcat, 2560, 2, nullptr, 0);
        }
    }

    // ---- all preds in one big GEMM over hh[1..TT] ----
    preds_gemm<<<dim3(157, TT), 256, 0, stream>>>(hh + (size_t)BB * 512, WpF, b_fc, lens, out);
}